// Round 1
// baseline (12942.706 us; speedup 1.0000x reference)
//
#include <hip/hip_runtime.h>
#include <math.h>

#define TS 64
#define KT 16
#define PAD 4

// Generic C[M,N] = concatK(A1|A2) @ concatK(W1|W2)^T + bias1 + bias2, optional relu,
// optional elementwise multiplier. A1 rows may be gathered via idx1 (stride idx_stride).
__global__ __launch_bounds__(256)
void gemm_kernel(const float* __restrict__ A1, const int* __restrict__ idx1, int idx_stride,
                 int lda1, int k1,
                 const float* __restrict__ W1, int ldw1,
                 const float* __restrict__ A2, int lda2, int k2,
                 const float* __restrict__ W2, int ldw2,
                 const float* __restrict__ bias1, const float* __restrict__ bias2,
                 const float* __restrict__ mul,
                 float* __restrict__ C, int ldc, int M, int N, int do_relu)
{
    __shared__ float As[KT][TS + PAD];
    __shared__ float Ws[KT][TS + PAD];
    const int tid = threadIdx.x;
    const int m0 = blockIdx.y * TS;
    const int n0 = blockIdx.x * TS;
    const int Ktot = k1 + k2;
    const int lrow = tid >> 2;          // 0..63
    const int lk4 = (tid & 3) << 2;     // 0,4,8,12
    const int tx = tid & 15;
    const int ty = tid >> 4;

    float acc[4][4] = {{0.f}};

    const int rg = m0 + lrow;
    const bool rok = rg < M;
    const int ng = n0 + lrow;
    const bool nok = ng < N;
    int arow = 0;
    if (rok) arow = idx1 ? idx1[(size_t)rg * idx_stride] : rg;

    for (int kb = 0; kb < Ktot; kb += KT) {
#pragma unroll
        for (int u = 0; u < 4; ++u) {
            int kg = kb + lk4 + u;
            float va = 0.f, vw = 0.f;
            if (rok && kg < Ktot) {
                va = (kg < k1) ? A1[(size_t)arow * lda1 + kg]
                               : A2[(size_t)rg * lda2 + (kg - k1)];
            }
            if (nok && kg < Ktot) {
                vw = (kg < k1) ? W1[(size_t)ng * ldw1 + kg]
                               : W2[(size_t)ng * ldw2 + (kg - k1)];
            }
            As[lk4 + u][lrow] = va;
            Ws[lk4 + u][lrow] = vw;
        }
        __syncthreads();
#pragma unroll
        for (int kk = 0; kk < KT; ++kk) {
            float a[4], b[4];
#pragma unroll
            for (int i = 0; i < 4; ++i) a[i] = As[kk][(ty << 2) + i];
#pragma unroll
            for (int j = 0; j < 4; ++j) b[j] = Ws[kk][(tx << 2) + j];
#pragma unroll
            for (int i = 0; i < 4; ++i)
#pragma unroll
                for (int j = 0; j < 4; ++j)
                    acc[i][j] = fmaf(a[i], b[j], acc[i][j]);
        }
        __syncthreads();
    }

#pragma unroll
    for (int i = 0; i < 4; ++i) {
        int m = m0 + (ty << 2) + i;
        if (m >= M) continue;
#pragma unroll
        for (int j = 0; j < 4; ++j) {
            int n = n0 + (tx << 2) + j;
            if (n >= N) continue;
            float v = acc[i][j];
            if (bias1) v += bias1[n];
            if (bias2) v += bias2[n];
            if (do_relu) v = fmaxf(v, 0.f);
            if (mul) v *= mul[(size_t)m * ldc + n];
            C[(size_t)m * ldc + n] = v;
        }
    }
}

// gates: [1536, 2048] (i,f,g,o); h,c: [1536,512]
__global__ __launch_bounds__(256)
void lstm_cell_kernel(const float* __restrict__ gates, float* __restrict__ h, float* __restrict__ c)
{
    int id = blockIdx.x * 256 + threadIdx.x;      // < 1536*512
    int n = id >> 9, hh = id & 511;
    const float* g = gates + ((size_t)n << 11);
    float iv = g[hh], fv = g[512 + hh], gv = g[1024 + hh], ov = g[1536 + hh];
    float si = 1.f / (1.f + expf(-iv));
    float sf = 1.f / (1.f + expf(-fv));
    float so = 1.f / (1.f + expf(-ov));
    float cv = sf * c[id] + si * tanhf(gv);
    c[id] = cv;
    h[id] = so * tanhf(cv);
}

// Fused: logits[k] = sum_h relu(img[n,k,:]·vW[h,:] + vb[h]) * (qproj[n,h]*oW[h]);
// softmax over k; v_emb[n,h] = sum_k att[k]*img[n,k,h].  (ob dropped: softmax shift-invariant)
#define ETILE 16
__global__ __launch_bounds__(256)
void attn_kernel(const float* __restrict__ img, const float* __restrict__ vW,
                 const float* __restrict__ vb, const float* __restrict__ qproj,
                 const float* __restrict__ oW, float* __restrict__ v_emb)
{
    __shared__ float simg[49][512];          // 100352 B
    __shared__ float svw[256][ETILE + 1];    // 17408 B
    __shared__ float swq[512];
    __shared__ float svb[512];
    __shared__ float slog[56];
    const int tid = threadIdx.x;
    const int n = blockIdx.x;
    const float* ip = img + (size_t)n * (49 * 512);
    for (int i = tid; i < 49 * 512; i += 256) simg[i >> 9][i & 511] = ip[i];
    for (int hh = tid; hh < 512; hh += 256) {
        swq[hh] = qproj[(size_t)n * 512 + hh] * oW[hh];
        svb[hh] = vb[hh];
    }
    if (tid < 56) slog[tid] = 0.f;
    __syncthreads();
    const int hl = tid & 63;     // h within 64-slab (== lane)
    const int kg = tid >> 6;     // wave id = k residue class
    const int nk = (kg == 0) ? 13 : 12;   // k = kg + 4*ki < 49
    for (int hb0 = 0; hb0 < 512; hb0 += 256) {
        float acc[13][4];
#pragma unroll
        for (int a = 0; a < 13; ++a)
#pragma unroll
            for (int b = 0; b < 4; ++b) acc[a][b] = 0.f;
        for (int e0 = 0; e0 < 512; e0 += ETILE) {
            __syncthreads();
            {   // stage vW[hb0+tid][e0..e0+15]
                const float4* wp4 = (const float4*)(vW + (size_t)(hb0 + tid) * 512 + e0);
#pragma unroll
                for (int q = 0; q < ETILE / 4; ++q) {
                    float4 v = wp4[q];
                    svw[tid][q * 4 + 0] = v.x;
                    svw[tid][q * 4 + 1] = v.y;
                    svw[tid][q * 4 + 2] = v.z;
                    svw[tid][q * 4 + 3] = v.w;
                }
            }
            __syncthreads();
#pragma unroll
            for (int e = 0; e < ETILE; ++e) {
                float w0 = svw[hl][e];
                float w1 = svw[64 + hl][e];
                float w2 = svw[128 + hl][e];
                float w3 = svw[192 + hl][e];
#pragma unroll
                for (int ki = 0; ki < 13; ++ki) {
                    if (ki < nk) {
                        float a = simg[kg + (ki << 2)][e0 + e];
                        acc[ki][0] = fmaf(a, w0, acc[ki][0]);
                        acc[ki][1] = fmaf(a, w1, acc[ki][1]);
                        acc[ki][2] = fmaf(a, w2, acc[ki][2]);
                        acc[ki][3] = fmaf(a, w3, acc[ki][3]);
                    }
                }
            }
        }
        for (int ki = 0; ki < nk; ++ki) {
            int k = kg + (ki << 2);
            float s = 0.f;
#pragma unroll
            for (int hq = 0; hq < 4; ++hq) {
                int hh = hb0 + hq * 64 + hl;
                float v = acc[ki][hq] + svb[hh];
                v = fmaxf(v, 0.f);
                s += v * swq[hh];
            }
#pragma unroll
            for (int off = 32; off; off >>= 1) s += __shfl_down(s, off, 64);
            if (hl == 0) slog[k] += s;   // unique k per wave: no race
        }
    }
    __syncthreads();
    if (tid == 0) {
        float mx = -1e30f;
        for (int k = 0; k < 49; ++k) mx = fmaxf(mx, slog[k]);
        float sum = 0.f;
        for (int k = 0; k < 49; ++k) { float e = expf(slog[k] - mx); slog[k] = e; sum += e; }
        float inv = 1.f / sum;
        for (int k = 0; k < 49; ++k) slog[k] *= inv;
    }
    __syncthreads();
    for (int hh = tid; hh < 512; hh += 256) {
        float s = 0.f;
        for (int k = 0; k < 49; ++k) s = fmaf(slog[k], simg[k][hh], s);
        v_emb[(size_t)n * 512 + hh] = s;
    }
}

// g0[b,i,j,c] = relu(P[b*6+j,c] + Q[b*6+i,c] + b0[c])
__global__ __launch_bounds__(256)
void g0build_kernel(const float* __restrict__ P, const float* __restrict__ Q,
                    const float* __restrict__ b0, float* __restrict__ g0)
{
    int id = blockIdx.x * 256 + threadIdx.x;   // < 9216*512
    int cc = id & 511;
    int r = id >> 9;
    int j = r % 6;
    int t = r / 6;
    int i = t % 6;
    int b = t / 6;
    float v = P[((size_t)(b * 6 + j) << 9) + cc] + Q[((size_t)(b * 6 + i) << 9) + cc] + b0[cc];
    g0[id] = fmaxf(v, 0.f);
}

__global__ __launch_bounds__(256)
void gsum_kernel(const float* __restrict__ g, float* __restrict__ out)
{
    int id = blockIdx.x * 256 + threadIdx.x;   // < 256*512
    int b = id >> 9, hh = id & 511;
    const float* p = g + (size_t)b * 36 * 512 + hh;
    float s = 0.f;
#pragma unroll
    for (int i = 0; i < 36; ++i) s += p[i * 512];
    out[id] = s;
}

__global__ __launch_bounds__(256)
void l2norm_kernel(const float* __restrict__ in, float* __restrict__ out)
{
    int b = blockIdx.x;
    int tid = threadIdx.x;
    float v0 = in[(size_t)b * 512 + tid];
    float v1 = in[(size_t)b * 512 + 256 + tid];
    float s = v0 * v0 + v1 * v1;
#pragma unroll
    for (int off = 32; off; off >>= 1) s += __shfl_down(s, off, 64);
    __shared__ float ps[4];
    if ((tid & 63) == 0) ps[tid >> 6] = s;
    __syncthreads();
    float tot = ps[0] + ps[1] + ps[2] + ps[3];
    float inv = 1.f / sqrtf(tot);
    out[(size_t)b * 512 + tid] = v0 * inv;
    out[(size_t)b * 512 + 256 + tid] = v1 * inv;
}

extern "C" void kernel_launch(void* const* d_in, const int* in_sizes, int n_in,
                              void* d_out, int out_size, void* d_ws, size_t ws_size,
                              hipStream_t stream)
{
    (void)in_sizes; (void)n_in; (void)out_size; (void)ws_size;
    const float* img    = (const float*)d_in[0];
    const int*   toks   = (const int*)d_in[1];
    const float* qword  = (const float*)d_in[2];
    const float* Wih_f  = (const float*)d_in[3];
    const float* Whh_f  = (const float*)d_in[4];
    const float* bih_f  = (const float*)d_in[5];
    const float* bhh_f  = (const float*)d_in[6];
    const float* Wih_b  = (const float*)d_in[7];
    const float* Whh_b  = (const float*)d_in[8];
    const float* bih_b  = (const float*)d_in[9];
    const float* bhh_b  = (const float*)d_in[10];
    const float* proj_W = (const float*)d_in[11];
    const float* proj_b = (const float*)d_in[12];
    const float* vatt_vW = (const float*)d_in[13];
    const float* vatt_vb = (const float*)d_in[14];
    const float* vatt_qW = (const float*)d_in[15];
    const float* vatt_qb = (const float*)d_in[16];
    const float* vatt_oW = (const float*)d_in[17];
    /* d_in[18] vatt_ob: dropped (softmax shift-invariance) */
    const float* qnet_W = (const float*)d_in[19];
    const float* qnet_b = (const float*)d_in[20];
    const float* vnet_W = (const float*)d_in[21];
    const float* vnet_b = (const float*)d_in[22];
    const float* cls_W1 = (const float*)d_in[23];
    const float* cls_b1 = (const float*)d_in[24];
    const float* cls_W2 = (const float*)d_in[25];
    const float* cls_b2 = (const float*)d_in[26];
    const float* g0_W   = (const float*)d_in[27];
    const float* g0_b   = (const float*)d_in[28];
    const float* g1_W   = (const float*)d_in[29];
    const float* g1_b   = (const float*)d_in[30];
    const float* g2_W   = (const float*)d_in[31];
    const float* g2_b   = (const float*)d_in[32];
    const float* g3_W   = (const float*)d_in[33];
    const float* g3_b   = (const float*)d_in[34];
    const float* f0_W   = (const float*)d_in[35];
    const float* f0_b   = (const float*)d_in[36];
    const float* f1_W   = (const float*)d_in[37];
    const float* f1_b   = (const float*)d_in[38];

    float* out_logits = (float*)d_out;                  // [1536,2001]
    float* out_rec    = (float*)d_out + 1536 * 2001;    // [256,512]

    float* ws = (float*)d_ws;
    size_t off = 0;
    auto alloc = [&](size_t nf) { float* p = ws + off; off += nf; return p; };
    float* region0 = alloc((size_t)9216 * 512);  // gates [1536,2048] / hid1 [1536,1024] / gA [9216,512] (phase-disjoint)
    float* h_f    = alloc((size_t)1536 * 512);
    float* h_b    = alloc((size_t)1536 * 512);
    float* cbuf   = alloc((size_t)1536 * 512);
    float* q_emb  = alloc((size_t)1536 * 512);
    float* q_proj = alloc((size_t)1536 * 512);
    float* v_emb  = alloc((size_t)1536 * 512);
    float* q_repr = alloc((size_t)1536 * 512);
    float* joint  = alloc((size_t)1536 * 512);
    float* Pb     = alloc((size_t)1536 * 512);
    float* Qb     = alloc((size_t)1536 * 512);
    float* gB     = alloc((size_t)9216 * 512);
    float* gsum_b = alloc((size_t)256 * 512);
    float* f0o    = alloc((size_t)256 * 512);
    float* rect   = alloc((size_t)256 * 512);

    float* gates = region0;
    float* hid1  = region0;
    float* gA    = region0;

    auto gemm = [&](const float* A1, const int* idx1, int idxs, int lda1, int k1,
                    const float* W1, int ldw1,
                    const float* A2, int lda2, int k2, const float* W2, int ldw2,
                    const float* b1, const float* b2, const float* mulp,
                    float* Cp, int ldc, int M, int N, int relu) {
        dim3 g((N + TS - 1) / TS, (M + TS - 1) / TS);
        hipLaunchKernelGGL(gemm_kernel, g, dim3(256), 0, stream,
                           A1, idx1, idxs, lda1, k1, W1, ldw1, A2, lda2, k2, W2, ldw2,
                           b1, b2, mulp, Cp, ldc, M, N, relu);
    };

    const int NR = 1536;
    // ---- bidirectional LSTM ----
    hipMemsetAsync(h_f, 0, (size_t)NR * 512 * sizeof(float), stream);
    hipMemsetAsync(cbuf, 0, (size_t)NR * 512 * sizeof(float), stream);
    for (int t = 0; t < 10; ++t) {
        gemm(qword, toks + t, 10, 300, 300, Wih_f, 300,
             h_f, 512, 512, Whh_f, 512,
             bih_f, bhh_f, nullptr, gates, 2048, NR, 2048, 0);
        hipLaunchKernelGGL(lstm_cell_kernel, dim3(3072), dim3(256), 0, stream, gates, h_f, cbuf);
    }
    hipMemsetAsync(h_b, 0, (size_t)NR * 512 * sizeof(float), stream);
    hipMemsetAsync(cbuf, 0, (size_t)NR * 512 * sizeof(float), stream);
    for (int t = 0; t < 10; ++t) {
        gemm(qword, toks + (9 - t), 10, 300, 300, Wih_b, 300,
             h_b, 512, 512, Whh_b, 512,
             bih_b, bhh_b, nullptr, gates, 2048, NR, 2048, 0);
        hipLaunchKernelGGL(lstm_cell_kernel, dim3(3072), dim3(256), 0, stream, gates, h_b, cbuf);
    }
    // q_emb = [h_f|h_b] @ proj_W^T + proj_b   (proj_W is [512,1024])
    gemm(h_f, nullptr, 0, 512, 512, proj_W, 1024,
         h_b, 512, 512, proj_W + 512, 1024,
         proj_b, nullptr, nullptr, q_emb, 512, NR, 512, 0);
    // q_proj = relu(q_emb @ vatt_qW^T + qb)
    gemm(q_emb, nullptr, 0, 512, 512, vatt_qW, 512,
         nullptr, 0, 0, nullptr, 0,
         vatt_qb, nullptr, nullptr, q_proj, 512, NR, 512, 1);
    // fused attention -> v_emb
    hipLaunchKernelGGL(attn_kernel, dim3(1536), dim3(256), 0, stream,
                       img, vatt_vW, vatt_vb, q_proj, vatt_oW, v_emb);
    // joint = relu(q_emb@qnet^T+b) * relu(v_emb@vnet^T+b)
    gemm(q_emb, nullptr, 0, 512, 512, qnet_W, 512, nullptr, 0, 0, nullptr, 0,
         qnet_b, nullptr, nullptr, q_repr, 512, NR, 512, 1);
    gemm(v_emb, nullptr, 0, 512, 512, vnet_W, 512, nullptr, 0, 0, nullptr, 0,
         vnet_b, nullptr, q_repr, joint, 512, NR, 512, 1);
    // classifier
    gemm(joint, nullptr, 0, 512, 512, cls_W1, 512, nullptr, 0, 0, nullptr, 0,
         cls_b1, nullptr, nullptr, hid1, 1024, NR, 1024, 1);
    gemm(hid1, nullptr, 0, 1024, 1024, cls_W2, 1024, nullptr, 0, 0, nullptr, 0,
         cls_b2, nullptr, nullptr, out_logits, 2001, NR, 2001, 0);
    // relation network: g0 factored via P (g0_W[:, :512]) and Q (g0_W[:, 512:])
    gemm(joint, nullptr, 0, 512, 512, g0_W, 1024, nullptr, 0, 0, nullptr, 0,
         nullptr, nullptr, nullptr, Pb, 512, NR, 512, 0);
    gemm(joint, nullptr, 0, 512, 512, g0_W + 512, 1024, nullptr, 0, 0, nullptr, 0,
         nullptr, nullptr, nullptr, Qb, 512, NR, 512, 0);
    hipLaunchKernelGGL(g0build_kernel, dim3(18432), dim3(256), 0, stream, Pb, Qb, g0_b, gA);
    gemm(gA, nullptr, 0, 512, 512, g1_W, 512, nullptr, 0, 0, nullptr, 0,
         g1_b, nullptr, nullptr, gB, 512, 9216, 512, 1);
    gemm(gB, nullptr, 0, 512, 512, g2_W, 512, nullptr, 0, 0, nullptr, 0,
         g2_b, nullptr, nullptr, gA, 512, 9216, 512, 1);
    gemm(gA, nullptr, 0, 512, 512, g3_W, 512, nullptr, 0, 0, nullptr, 0,
         g3_b, nullptr, nullptr, gB, 512, 9216, 512, 1);
    hipLaunchKernelGGL(gsum_kernel, dim3(512), dim3(256), 0, stream, gB, gsum_b);
    gemm(gsum_b, nullptr, 0, 512, 512, f0_W, 512, nullptr, 0, 0, nullptr, 0,
         f0_b, nullptr, nullptr, f0o, 512, 256, 512, 1);
    gemm(f0o, nullptr, 0, 512, 512, f1_W, 512, nullptr, 0, 0, nullptr, 0,
         f1_b, nullptr, nullptr, rect, 512, 256, 512, 0);
    hipLaunchKernelGGL(l2norm_kernel, dim3(256), dim3(256), 0, stream, rect, out_rec);
}

// Round 2
// 4837.939 us; speedup vs baseline: 2.6753x; 2.6753x over previous
//
#include <hip/hip_runtime.h>
#include <math.h>

#define TS 64
#define KT 16
#define PAD 4

// Generic C[M,N] = concatK(A1|A2) @ concatK(W1|W2)^T + bias1 + bias2, optional relu,
// optional elementwise multiplier. A1 rows may be gathered via idx1 (stride idx_stride).
__global__ __launch_bounds__(256)
void gemm_kernel(const float* __restrict__ A1, const int* __restrict__ idx1, int idx_stride,
                 int lda1, int k1,
                 const float* __restrict__ W1, int ldw1,
                 const float* __restrict__ A2, int lda2, int k2,
                 const float* __restrict__ W2, int ldw2,
                 const float* __restrict__ bias1, const float* __restrict__ bias2,
                 const float* __restrict__ mul,
                 float* __restrict__ C, int ldc, int M, int N, int do_relu)
{
    __shared__ float As[KT][TS + PAD];
    __shared__ float Ws[KT][TS + PAD];
    const int tid = threadIdx.x;
    const int m0 = blockIdx.y * TS;
    const int n0 = blockIdx.x * TS;
    const int Ktot = k1 + k2;
    const int lrow = tid >> 2;          // 0..63
    const int lk4 = (tid & 3) << 2;     // 0,4,8,12
    const int tx = tid & 15;
    const int ty = tid >> 4;

    float acc[4][4] = {{0.f}};

    const int rg = m0 + lrow;
    const bool rok = rg < M;
    const int ng = n0 + lrow;
    const bool nok = ng < N;
    int arow = 0;
    if (rok) arow = idx1 ? idx1[(size_t)rg * idx_stride] : rg;

    for (int kb = 0; kb < Ktot; kb += KT) {
#pragma unroll
        for (int u = 0; u < 4; ++u) {
            int kg = kb + lk4 + u;
            float va = 0.f, vw = 0.f;
            if (rok && kg < Ktot) {
                va = (kg < k1) ? A1[(size_t)arow * lda1 + kg]
                               : A2[(size_t)rg * lda2 + (kg - k1)];
            }
            if (nok && kg < Ktot) {
                vw = (kg < k1) ? W1[(size_t)ng * ldw1 + kg]
                               : W2[(size_t)ng * ldw2 + (kg - k1)];
            }
            As[lk4 + u][lrow] = va;
            Ws[lk4 + u][lrow] = vw;
        }
        __syncthreads();
#pragma unroll
        for (int kk = 0; kk < KT; ++kk) {
            float a[4], b[4];
#pragma unroll
            for (int i = 0; i < 4; ++i) a[i] = As[kk][(ty << 2) + i];
#pragma unroll
            for (int j = 0; j < 4; ++j) b[j] = Ws[kk][(tx << 2) + j];
#pragma unroll
            for (int i = 0; i < 4; ++i)
#pragma unroll
                for (int j = 0; j < 4; ++j)
                    acc[i][j] = fmaf(a[i], b[j], acc[i][j]);
        }
        __syncthreads();
    }

#pragma unroll
    for (int i = 0; i < 4; ++i) {
        int m = m0 + (ty << 2) + i;
        if (m >= M) continue;
#pragma unroll
        for (int j = 0; j < 4; ++j) {
            int n = n0 + (tx << 2) + j;
            if (n >= N) continue;
            float v = acc[i][j];
            if (bias1) v += bias1[n];
            if (bias2) v += bias2[n];
            if (do_relu) v = fmaxf(v, 0.f);
            if (mul) v *= mul[(size_t)m * ldc + n];
            C[(size_t)m * ldc + n] = v;
        }
    }
}

// gates: [1536, 2048] (i,f,g,o); h,c: [1536,512]
__global__ __launch_bounds__(256)
void lstm_cell_kernel(const float* __restrict__ gates, float* __restrict__ h, float* __restrict__ c)
{
    int id = blockIdx.x * 256 + threadIdx.x;      // < 1536*512
    int n = id >> 9, hh = id & 511;
    const float* g = gates + ((size_t)n << 11);
    float iv = g[hh], fv = g[512 + hh], gv = g[1024 + hh], ov = g[1536 + hh];
    float si = 1.f / (1.f + expf(-iv));
    float sf = 1.f / (1.f + expf(-fv));
    float so = 1.f / (1.f + expf(-ov));
    float cv = sf * c[id] + si * tanhf(gv);
    c[id] = cv;
    h[id] = so * tanhf(cv);
}

// swq[n,h] = qproj[n,h] * oW[h]
__global__ __launch_bounds__(256)
void swq_kernel(const float* __restrict__ qproj, const float* __restrict__ oW,
                float* __restrict__ swq)
{
    int id = blockIdx.x * 256 + threadIdx.x;   // < 1536*512
    swq[id] = qproj[id] * oW[id & 511];
}

// logits[m] = sum_{h=0..511} relu(img[m,:]·vW[h,:] + vb[h]) * swq[m/49, h]
// M = 75264 rows (n*49+k). Each block: 64 rows x full 512 cols via 8 chunks of 64.
__global__ __launch_bounds__(256)
void attn_logits_kernel(const float* __restrict__ img, const float* __restrict__ vW,
                        const float* __restrict__ vb, const float* __restrict__ swq,
                        float* __restrict__ logits)
{
    __shared__ float As[KT][TS + PAD];
    __shared__ float Ws[KT][TS + PAD];
    __shared__ float sred[TS][17];
    const int tid = threadIdx.x;
    const int m0 = blockIdx.x * TS;
    const int lrow = tid >> 2;
    const int lk4 = (tid & 3) << 2;
    const int tx = tid & 15;
    const int ty = tid >> 4;
    const int arow = m0 + lrow;

    int nidx[4];
#pragma unroll
    for (int i = 0; i < 4; ++i) nidx[i] = (m0 + (ty << 2) + i) / 49;
    float ps[4] = {0.f, 0.f, 0.f, 0.f};

    for (int nb = 0; nb < 512; nb += TS) {
        float acc[4][4] = {{0.f}};
        for (int kb = 0; kb < 512; kb += KT) {
            __syncthreads();
#pragma unroll
            for (int u = 0; u < 4; ++u) {
                int kg = kb + lk4 + u;
                As[lk4 + u][lrow] = img[(size_t)arow * 512 + kg];
                Ws[lk4 + u][lrow] = vW[(size_t)(nb + lrow) * 512 + kg];
            }
            __syncthreads();
#pragma unroll
            for (int kk = 0; kk < KT; ++kk) {
                float a[4], b[4];
#pragma unroll
                for (int i = 0; i < 4; ++i) a[i] = As[kk][(ty << 2) + i];
#pragma unroll
                for (int j = 0; j < 4; ++j) b[j] = Ws[kk][(tx << 2) + j];
#pragma unroll
                for (int i = 0; i < 4; ++i)
#pragma unroll
                    for (int j = 0; j < 4; ++j)
                        acc[i][j] = fmaf(a[i], b[j], acc[i][j]);
            }
        }
        // epilogue for this 64-col chunk: relu(+vb) * swq, reduce over cols
#pragma unroll
        for (int i = 0; i < 4; ++i) {
            const float* sq = swq + (size_t)nidx[i] * 512 + nb;
#pragma unroll
            for (int j = 0; j < 4; ++j) {
                int c = (tx << 2) + j;
                float v = acc[i][j] + vb[nb + c];
                v = fmaxf(v, 0.f);
                ps[i] = fmaf(v, sq[c], ps[i]);
            }
        }
    }
#pragma unroll
    for (int i = 0; i < 4; ++i) sred[(ty << 2) + i][tx] = ps[i];
    __syncthreads();
    if (tid < TS) {
        float s = 0.f;
#pragma unroll
        for (int t = 0; t < 16; ++t) s += sred[tid][t];
        logits[(size_t)(m0 + tid)] = s;
    }
}

// softmax over k (49) per n, then v_emb[n,h] = sum_k att[k]*img[n,k,h]
__global__ __launch_bounds__(256)
void attn_vemb_kernel(const float* __restrict__ logits, const float* __restrict__ img,
                      float* __restrict__ v_emb)
{
    __shared__ float satt[49];
    const int n = blockIdx.x;
    const int tid = threadIdx.x;
    if (tid < 64) {
        float v = (tid < 49) ? logits[(size_t)n * 49 + tid] : -1e30f;
        float m = v;
#pragma unroll
        for (int off = 32; off; off >>= 1) m = fmaxf(m, __shfl_xor(m, off, 64));
        float e = (tid < 49) ? expf(v - m) : 0.f;
        float s = e;
#pragma unroll
        for (int off = 32; off; off >>= 1) s += __shfl_xor(s, off, 64);
        if (tid < 49) satt[tid] = e / s;
    }
    __syncthreads();
    const float2* ip = (const float2*)(img + (size_t)n * 49 * 512);
    float2 s2 = make_float2(0.f, 0.f);
    const int h2 = tid;   // 256 threads x float2 = 512 floats
    for (int k = 0; k < 49; ++k) {
        float2 v = ip[k * 256 + h2];
        float a = satt[k];
        s2.x = fmaf(a, v.x, s2.x);
        s2.y = fmaf(a, v.y, s2.y);
    }
    ((float2*)(v_emb + (size_t)n * 512))[h2] = s2;
}

// g0[b,i,j,c] = relu(P[b*6+j,c] + Q[b*6+i,c] + b0[c])
__global__ __launch_bounds__(256)
void g0build_kernel(const float* __restrict__ P, const float* __restrict__ Q,
                    const float* __restrict__ b0, float* __restrict__ g0)
{
    int id = blockIdx.x * 256 + threadIdx.x;   // < 9216*512
    int cc = id & 511;
    int r = id >> 9;
    int j = r % 6;
    int t = r / 6;
    int i = t % 6;
    int b = t / 6;
    float v = P[((size_t)(b * 6 + j) << 9) + cc] + Q[((size_t)(b * 6 + i) << 9) + cc] + b0[cc];
    g0[id] = fmaxf(v, 0.f);
}

__global__ __launch_bounds__(256)
void gsum_kernel(const float* __restrict__ g, float* __restrict__ out)
{
    int id = blockIdx.x * 256 + threadIdx.x;   // < 256*512
    int b = id >> 9, hh = id & 511;
    const float* p = g + (size_t)b * 36 * 512 + hh;
    float s = 0.f;
#pragma unroll
    for (int i = 0; i < 36; ++i) s += p[i * 512];
    out[id] = s;
}

__global__ __launch_bounds__(256)
void l2norm_kernel(const float* __restrict__ in, float* __restrict__ out)
{
    int b = blockIdx.x;
    int tid = threadIdx.x;
    float v0 = in[(size_t)b * 512 + tid];
    float v1 = in[(size_t)b * 512 + 256 + tid];
    float s = v0 * v0 + v1 * v1;
#pragma unroll
    for (int off = 32; off; off >>= 1) s += __shfl_down(s, off, 64);
    __shared__ float ps[4];
    if ((tid & 63) == 0) ps[tid >> 6] = s;
    __syncthreads();
    float tot = ps[0] + ps[1] + ps[2] + ps[3];
    float inv = 1.f / sqrtf(tot);
    out[(size_t)b * 512 + tid] = v0 * inv;
    out[(size_t)b * 512 + 256 + tid] = v1 * inv;
}

extern "C" void kernel_launch(void* const* d_in, const int* in_sizes, int n_in,
                              void* d_out, int out_size, void* d_ws, size_t ws_size,
                              hipStream_t stream)
{
    (void)in_sizes; (void)n_in; (void)out_size; (void)ws_size;
    const float* img    = (const float*)d_in[0];
    const int*   toks   = (const int*)d_in[1];
    const float* qword  = (const float*)d_in[2];
    const float* Wih_f  = (const float*)d_in[3];
    const float* Whh_f  = (const float*)d_in[4];
    const float* bih_f  = (const float*)d_in[5];
    const float* bhh_f  = (const float*)d_in[6];
    const float* Wih_b  = (const float*)d_in[7];
    const float* Whh_b  = (const float*)d_in[8];
    const float* bih_b  = (const float*)d_in[9];
    const float* bhh_b  = (const float*)d_in[10];
    const float* proj_W = (const float*)d_in[11];
    const float* proj_b = (const float*)d_in[12];
    const float* vatt_vW = (const float*)d_in[13];
    const float* vatt_vb = (const float*)d_in[14];
    const float* vatt_qW = (const float*)d_in[15];
    const float* vatt_qb = (const float*)d_in[16];
    const float* vatt_oW = (const float*)d_in[17];
    /* d_in[18] vatt_ob: dropped (softmax shift-invariance) */
    const float* qnet_W = (const float*)d_in[19];
    const float* qnet_b = (const float*)d_in[20];
    const float* vnet_W = (const float*)d_in[21];
    const float* vnet_b = (const float*)d_in[22];
    const float* cls_W1 = (const float*)d_in[23];
    const float* cls_b1 = (const float*)d_in[24];
    const float* cls_W2 = (const float*)d_in[25];
    const float* cls_b2 = (const float*)d_in[26];
    const float* g0_W   = (const float*)d_in[27];
    const float* g0_b   = (const float*)d_in[28];
    const float* g1_W   = (const float*)d_in[29];
    const float* g1_b   = (const float*)d_in[30];
    const float* g2_W   = (const float*)d_in[31];
    const float* g2_b   = (const float*)d_in[32];
    const float* g3_W   = (const float*)d_in[33];
    const float* g3_b   = (const float*)d_in[34];
    const float* f0_W   = (const float*)d_in[35];
    const float* f0_b   = (const float*)d_in[36];
    const float* f1_W   = (const float*)d_in[37];
    const float* f1_b   = (const float*)d_in[38];

    float* out_logits = (float*)d_out;                  // [1536,2001]
    float* out_rec    = (float*)d_out + 1536 * 2001;    // [256,512]

    float* ws = (float*)d_ws;
    size_t off = 0;
    auto alloc = [&](size_t nf) { float* p = ws + off; off += nf; return p; };
    float* region0 = alloc((size_t)9216 * 512);  // gates [1536,2048] / hid1 [1536,1024] / gA [9216,512]
    float* h_f    = alloc((size_t)1536 * 512);
    float* h_b    = alloc((size_t)1536 * 512);
    float* cbuf   = alloc((size_t)1536 * 512);
    float* q_emb  = alloc((size_t)1536 * 512);
    float* q_proj = alloc((size_t)1536 * 512);
    float* v_emb  = alloc((size_t)1536 * 512);
    float* q_repr = alloc((size_t)1536 * 512);
    float* joint  = alloc((size_t)1536 * 512);
    float* Pb     = alloc((size_t)1536 * 512);
    float* Qb     = alloc((size_t)1536 * 512);
    float* gB     = alloc((size_t)9216 * 512);
    float* gsum_b = alloc((size_t)256 * 512);
    float* f0o    = alloc((size_t)256 * 512);
    float* rect   = alloc((size_t)256 * 512);
    float* swq    = alloc((size_t)1536 * 512);
    float* logit49 = alloc((size_t)75264);

    float* gates = region0;
    float* hid1  = region0;
    float* gA    = region0;

    auto gemm = [&](const float* A1, const int* idx1, int idxs, int lda1, int k1,
                    const float* W1, int ldw1,
                    const float* A2, int lda2, int k2, const float* W2, int ldw2,
                    const float* b1, const float* b2, const float* mulp,
                    float* Cp, int ldc, int M, int N, int relu) {
        dim3 g((N + TS - 1) / TS, (M + TS - 1) / TS);
        hipLaunchKernelGGL(gemm_kernel, g, dim3(256), 0, stream,
                           A1, idx1, idxs, lda1, k1, W1, ldw1, A2, lda2, k2, W2, ldw2,
                           b1, b2, mulp, Cp, ldc, M, N, relu);
    };

    const int NR = 1536;
    // ---- bidirectional LSTM ----
    hipMemsetAsync(h_f, 0, (size_t)NR * 512 * sizeof(float), stream);
    hipMemsetAsync(cbuf, 0, (size_t)NR * 512 * sizeof(float), stream);
    for (int t = 0; t < 10; ++t) {
        gemm(qword, toks + t, 10, 300, 300, Wih_f, 300,
             h_f, 512, 512, Whh_f, 512,
             bih_f, bhh_f, nullptr, gates, 2048, NR, 2048, 0);
        hipLaunchKernelGGL(lstm_cell_kernel, dim3(3072), dim3(256), 0, stream, gates, h_f, cbuf);
    }
    hipMemsetAsync(h_b, 0, (size_t)NR * 512 * sizeof(float), stream);
    hipMemsetAsync(cbuf, 0, (size_t)NR * 512 * sizeof(float), stream);
    for (int t = 0; t < 10; ++t) {
        gemm(qword, toks + (9 - t), 10, 300, 300, Wih_b, 300,
             h_b, 512, 512, Whh_b, 512,
             bih_b, bhh_b, nullptr, gates, 2048, NR, 2048, 0);
        hipLaunchKernelGGL(lstm_cell_kernel, dim3(3072), dim3(256), 0, stream, gates, h_b, cbuf);
    }
    // q_emb = [h_f|h_b] @ proj_W^T + proj_b
    gemm(h_f, nullptr, 0, 512, 512, proj_W, 1024,
         h_b, 512, 512, proj_W + 512, 1024,
         proj_b, nullptr, nullptr, q_emb, 512, NR, 512, 0);
    // q_proj = relu(q_emb @ vatt_qW^T + qb)
    gemm(q_emb, nullptr, 0, 512, 512, vatt_qW, 512,
         nullptr, 0, 0, nullptr, 0,
         vatt_qb, nullptr, nullptr, q_proj, 512, NR, 512, 1);
    // attention: swq -> fused logits GEMM -> softmax + v_emb
    hipLaunchKernelGGL(swq_kernel, dim3(3072), dim3(256), 0, stream, q_proj, vatt_oW, swq);
    hipLaunchKernelGGL(attn_logits_kernel, dim3(1176), dim3(256), 0, stream,
                       img, vatt_vW, vatt_vb, swq, logit49);
    hipLaunchKernelGGL(attn_vemb_kernel, dim3(1536), dim3(256), 0, stream,
                       logit49, img, v_emb);
    // joint = relu(q_emb@qnet^T+b) * relu(v_emb@vnet^T+b)
    gemm(q_emb, nullptr, 0, 512, 512, qnet_W, 512, nullptr, 0, 0, nullptr, 0,
         qnet_b, nullptr, nullptr, q_repr, 512, NR, 512, 1);
    gemm(v_emb, nullptr, 0, 512, 512, vnet_W, 512, nullptr, 0, 0, nullptr, 0,
         vnet_b, nullptr, q_repr, joint, 512, NR, 512, 1);
    // classifier
    gemm(joint, nullptr, 0, 512, 512, cls_W1, 512, nullptr, 0, 0, nullptr, 0,
         cls_b1, nullptr, nullptr, hid1, 1024, NR, 1024, 1);
    gemm(hid1, nullptr, 0, 1024, 1024, cls_W2, 1024, nullptr, 0, 0, nullptr, 0,
         cls_b2, nullptr, nullptr, out_logits, 2001, NR, 2001, 0);
    // relation network: g0 factored via P (g0_W[:, :512]) and Q (g0_W[:, 512:])
    gemm(joint, nullptr, 0, 512, 512, g0_W, 1024, nullptr, 0, 0, nullptr, 0,
         nullptr, nullptr, nullptr, Pb, 512, NR, 512, 0);
    gemm(joint, nullptr, 0, 512, 512, g0_W + 512, 1024, nullptr, 0, 0, nullptr, 0,
         nullptr, nullptr, nullptr, Qb, 512, NR, 512, 0);
    hipLaunchKernelGGL(g0build_kernel, dim3(18432), dim3(256), 0, stream, Pb, Qb, g0_b, gA);
    gemm(gA, nullptr, 0, 512, 512, g1_W, 512, nullptr, 0, 0, nullptr, 0,
         g1_b, nullptr, nullptr, gB, 512, 9216, 512, 1);
    gemm(gB, nullptr, 0, 512, 512, g2_W, 512, nullptr, 0, 0, nullptr, 0,
         g2_b, nullptr, nullptr, gA, 512, 9216, 512, 1);
    gemm(gA, nullptr, 0, 512, 512, g3_W, 512, nullptr, 0, 0, nullptr, 0,
         g3_b, nullptr, nullptr, gB, 512, 9216, 512, 1);
    hipLaunchKernelGGL(gsum_kernel, dim3(512), dim3(256), 0, stream, gB, gsum_b);
    gemm(gsum_b, nullptr, 0, 512, 512, f0_W, 512, nullptr, 0, 0, nullptr, 0,
         f0_b, nullptr, nullptr, f0o, 512, 256, 512, 1);
    gemm(f0o, nullptr, 0, 512, 512, f1_W, 512, nullptr, 0, 0, nullptr, 0,
         f1_b, nullptr, nullptr, rect, 512, 256, 512, 0);
    hipLaunchKernelGGL(l2norm_kernel, dim3(256), dim3(256), 0, stream, rect, out_rec);
}

// Round 3
// 1401.304 us; speedup vs baseline: 9.2362x; 3.4525x over previous
//
#include <hip/hip_runtime.h>
#include <hip/hip_bf16.h>
#include <math.h>

typedef __attribute__((ext_vector_type(8))) short short8;
typedef __attribute__((ext_vector_type(4))) float f32x4;

#define BT 64
#define KTILE 32
#define LSTR 40   // LDS row stride in bf16 elems (64+16B pad -> 2-way banks, free)

__device__ __forceinline__ short8 cvt8(const float* x) {
    short8 r;
#pragma unroll
    for (int i = 0; i < 8; ++i) {
        __hip_bfloat16 b = __float2bfloat16(x[i]);
        r[i] = *reinterpret_cast<const short*>(&b);
    }
    return r;
}

// Generic MFMA GEMM: C[M,N] = concatK(A1|A2) @ concatK(W1|W2)^T (+bias1+bias2, relu, *mul)
// A1 rows optionally gathered via idx1. mode 0: store C. mode 1 (attn): per-row
// reduce over cols of relu(acc+bias1[c]) * mul[(r/49)*ldc + c], store partial
// sums to C[r*gridDim.x + blockIdx.x].
__global__ __launch_bounds__(256)
void mfma_gemm_kernel(const float* __restrict__ A1, const int* __restrict__ idx1, int idx_stride,
                      int lda1, int k1,
                      const float* __restrict__ W1, int ldw1,
                      const float* __restrict__ A2, int lda2, int k2,
                      const float* __restrict__ W2, int ldw2,
                      const float* __restrict__ bias1, const float* __restrict__ bias2,
                      const float* __restrict__ mul,
                      float* __restrict__ C, int ldc, int M, int N, int do_relu, int mode)
{
    __shared__ short sA[2][BT][LSTR];
    __shared__ short sB[2][BT][LSTR];
    __shared__ float sred[BT][2];

    const int tid = threadIdx.x;
    const int m0 = blockIdx.y * BT;
    const int n0 = blockIdx.x * BT;
    const int Ktot = k1 + k2;
    const int srow = tid >> 2;            // 0..63 staging row
    const int skq  = (tid & 3) << 3;      // 0,8,16,24 staging k offset
    const int lane = tid & 63;
    const int wave = tid >> 6;
    const int wr = (wave >> 1) << 5;      // wave row origin in tile
    const int wc = (wave & 1) << 5;       // wave col origin in tile
    const int l15 = lane & 15;
    const int lh  = lane >> 4;

    const int rg = min(m0 + srow, M - 1);
    const int arow = idx1 ? idx1[(size_t)rg * idx_stride] : rg;
    const int ng = min(n0 + srow, N - 1);

    f32x4 acc[2][2];
#pragma unroll
    for (int m = 0; m < 2; ++m)
#pragma unroll
        for (int n = 0; n < 2; ++n)
            acc[m][n] = (f32x4){0.f, 0.f, 0.f, 0.f};

    const int nt = (Ktot + KTILE - 1) / KTILE;
    float a[8], w[8];

    auto loadregs = [&](int t) {
        const int kb = t * KTILE;
        if (kb + KTILE <= k1) {                    // fully in A1/W1
            const float* p = A1 + (size_t)arow * lda1 + kb + skq;
            float4 v0 = *(const float4*)p, v1 = *(const float4*)(p + 4);
            a[0]=v0.x; a[1]=v0.y; a[2]=v0.z; a[3]=v0.w; a[4]=v1.x; a[5]=v1.y; a[6]=v1.z; a[7]=v1.w;
            const float* q = W1 + (size_t)ng * ldw1 + kb + skq;
            float4 u0 = *(const float4*)q, u1 = *(const float4*)(q + 4);
            w[0]=u0.x; w[1]=u0.y; w[2]=u0.z; w[3]=u0.w; w[4]=u1.x; w[5]=u1.y; w[6]=u1.z; w[7]=u1.w;
        } else if (kb >= k1 && kb + KTILE <= Ktot) {   // fully in A2/W2
            const float* p = A2 + (size_t)rg * lda2 + (kb - k1) + skq;
            float4 v0 = *(const float4*)p, v1 = *(const float4*)(p + 4);
            a[0]=v0.x; a[1]=v0.y; a[2]=v0.z; a[3]=v0.w; a[4]=v1.x; a[5]=v1.y; a[6]=v1.z; a[7]=v1.w;
            const float* q = W2 + (size_t)ng * ldw2 + (kb - k1) + skq;
            float4 u0 = *(const float4*)q, u1 = *(const float4*)(q + 4);
            w[0]=u0.x; w[1]=u0.y; w[2]=u0.z; w[3]=u0.w; w[4]=u1.x; w[5]=u1.y; w[6]=u1.z; w[7]=u1.w;
        } else {                                   // straddle / tail: scalar + zero-fill
#pragma unroll
            for (int e = 0; e < 8; ++e) {
                int kg = kb + skq + e;
                float av = 0.f, wv = 0.f;
                if (kg < k1) {
                    av = A1[(size_t)arow * lda1 + kg];
                    wv = W1[(size_t)ng * ldw1 + kg];
                } else if (kg < Ktot) {
                    av = A2[(size_t)rg * lda2 + (kg - k1)];
                    wv = W2[(size_t)ng * ldw2 + (kg - k1)];
                }
                a[e] = av; w[e] = wv;
            }
        }
    };
    auto cvtwrite = [&](int buf) {
        *(short8*)&sA[buf][srow][skq] = cvt8(a);
        *(short8*)&sB[buf][srow][skq] = cvt8(w);
    };

    loadregs(0);
    cvtwrite(0);
    __syncthreads();

    for (int t = 0; t < nt; ++t) {
        const int cur = t & 1;
        if (t + 1 < nt) loadregs(t + 1);
        short8 af[2], bf[2];
#pragma unroll
        for (int m = 0; m < 2; ++m)
            af[m] = *(const short8*)&sA[cur][wr + (m << 4) + l15][lh << 3];
#pragma unroll
        for (int n = 0; n < 2; ++n)
            bf[n] = *(const short8*)&sB[cur][wc + (n << 4) + l15][lh << 3];
#pragma unroll
        for (int m = 0; m < 2; ++m)
#pragma unroll
            for (int n = 0; n < 2; ++n)
                acc[m][n] = __builtin_amdgcn_mfma_f32_16x16x32_bf16(af[m], bf[n], acc[m][n], 0, 0, 0);
        if (t + 1 < nt) cvtwrite(cur ^ 1);
        __syncthreads();
    }

    if (mode == 0) {
#pragma unroll
        for (int m = 0; m < 2; ++m) {
#pragma unroll
            for (int j = 0; j < 4; ++j) {
                const int r = m0 + wr + (m << 4) + (lh << 2) + j;
                if (r >= M) continue;
#pragma unroll
                for (int n = 0; n < 2; ++n) {
                    const int c = n0 + wc + (n << 4) + l15;
                    if (c >= N) continue;
                    float v = acc[m][n][j];
                    if (bias1) v += bias1[c];
                    if (bias2) v += bias2[c];
                    if (do_relu) v = fmaxf(v, 0.f);
                    if (mul) v *= mul[(size_t)r * ldc + c];
                    C[(size_t)r * ldc + c] = v;
                }
            }
        }
    } else {
        // attention col-reduce epilogue: bias1 = vb, mul = swq (stride ldc)
#pragma unroll
        for (int m = 0; m < 2; ++m) {
#pragma unroll
            for (int j = 0; j < 4; ++j) {
                const int rloc = wr + (m << 4) + (lh << 2) + j;
                const int r = m0 + rloc;
                const size_t sqbase = (size_t)(r / 49) * ldc;
                float s = 0.f;
#pragma unroll
                for (int n = 0; n < 2; ++n) {
                    const int c = n0 + wc + (n << 4) + l15;
                    float v = acc[m][n][j] + bias1[c];
                    v = fmaxf(v, 0.f);
                    s += v * mul[sqbase + c];
                }
                s += __shfl_xor(s, 1, 64);
                s += __shfl_xor(s, 2, 64);
                s += __shfl_xor(s, 4, 64);
                s += __shfl_xor(s, 8, 64);
                if (l15 == 0) sred[rloc][wc >> 5] = s;
            }
        }
        __syncthreads();
        if (tid < BT)
            C[(size_t)(m0 + tid) * gridDim.x + blockIdx.x] = sred[tid][0] + sred[tid][1];
    }
}

// gates: [1536, 2048] (i,f,g,o); h,c: [1536,512]
__global__ __launch_bounds__(256)
void lstm_cell_kernel(const float* __restrict__ gates, float* __restrict__ h, float* __restrict__ c)
{
    int id = blockIdx.x * 256 + threadIdx.x;      // < 1536*512
    int n = id >> 9, hh = id & 511;
    const float* g = gates + ((size_t)n << 11);
    float iv = g[hh], fv = g[512 + hh], gv = g[1024 + hh], ov = g[1536 + hh];
    float si = 1.f / (1.f + expf(-iv));
    float sf = 1.f / (1.f + expf(-fv));
    float so = 1.f / (1.f + expf(-ov));
    float cv = sf * c[id] + si * tanhf(gv);
    c[id] = cv;
    h[id] = so * tanhf(cv);
}

// swq[n,h] = qproj[n,h] * oW[h]
__global__ __launch_bounds__(256)
void swq_kernel(const float* __restrict__ qproj, const float* __restrict__ oW,
                float* __restrict__ swq)
{
    int id = blockIdx.x * 256 + threadIdx.x;   // < 1536*512
    swq[id] = qproj[id] * oW[id & 511];
}

// softmax over k (49) per n from 8-way partials, then v_emb[n,h] = sum_k att[k]*img[n,k,h]
__global__ __launch_bounds__(256)
void attn_vemb_kernel(const float* __restrict__ partial, const float* __restrict__ img,
                      float* __restrict__ v_emb)
{
    __shared__ float satt[49];
    const int n = blockIdx.x;
    const int tid = threadIdx.x;
    if (tid < 64) {
        float v = -1e30f;
        if (tid < 49) {
            const float* pp = partial + ((size_t)n * 49 + tid) * 8;
            v = ((pp[0] + pp[1]) + (pp[2] + pp[3])) + ((pp[4] + pp[5]) + (pp[6] + pp[7]));
        }
        float m = v;
#pragma unroll
        for (int off = 32; off; off >>= 1) m = fmaxf(m, __shfl_xor(m, off, 64));
        float e = (tid < 49) ? expf(v - m) : 0.f;
        float s = e;
#pragma unroll
        for (int off = 32; off; off >>= 1) s += __shfl_xor(s, off, 64);
        if (tid < 49) satt[tid] = e / s;
    }
    __syncthreads();
    const float2* ip = (const float2*)(img + (size_t)n * 49 * 512);
    float2 s2 = make_float2(0.f, 0.f);
    const int h2 = tid;
    for (int k = 0; k < 49; ++k) {
        float2 v = ip[k * 256 + h2];
        float a = satt[k];
        s2.x = fmaf(a, v.x, s2.x);
        s2.y = fmaf(a, v.y, s2.y);
    }
    ((float2*)(v_emb + (size_t)n * 512))[h2] = s2;
}

// g0[b,i,j,c] = relu(P[b*6+j,c] + Q[b*6+i,c] + b0[c])
__global__ __launch_bounds__(256)
void g0build_kernel(const float* __restrict__ P, const float* __restrict__ Q,
                    const float* __restrict__ b0, float* __restrict__ g0)
{
    int id = blockIdx.x * 256 + threadIdx.x;   // < 9216*512
    int cc = id & 511;
    int r = id >> 9;
    int j = r % 6;
    int t = r / 6;
    int i = t % 6;
    int b = t / 6;
    float v = P[((size_t)(b * 6 + j) << 9) + cc] + Q[((size_t)(b * 6 + i) << 9) + cc] + b0[cc];
    g0[id] = fmaxf(v, 0.f);
}

__global__ __launch_bounds__(256)
void gsum_kernel(const float* __restrict__ g, float* __restrict__ out)
{
    int id = blockIdx.x * 256 + threadIdx.x;   // < 256*512
    int b = id >> 9, hh = id & 511;
    const float* p = g + (size_t)b * 36 * 512 + hh;
    float s = 0.f;
#pragma unroll
    for (int i = 0; i < 36; ++i) s += p[i * 512];
    out[id] = s;
}

__global__ __launch_bounds__(256)
void l2norm_kernel(const float* __restrict__ in, float* __restrict__ out)
{
    int b = blockIdx.x;
    int tid = threadIdx.x;
    float v0 = in[(size_t)b * 512 + tid];
    float v1 = in[(size_t)b * 512 + 256 + tid];
    float s = v0 * v0 + v1 * v1;
#pragma unroll
    for (int off = 32; off; off >>= 1) s += __shfl_down(s, off, 64);
    __shared__ float ps[4];
    if ((tid & 63) == 0) ps[tid >> 6] = s;
    __syncthreads();
    float tot = ps[0] + ps[1] + ps[2] + ps[3];
    float inv = 1.f / sqrtf(tot);
    out[(size_t)b * 512 + tid] = v0 * inv;
    out[(size_t)b * 512 + 256 + tid] = v1 * inv;
}

extern "C" void kernel_launch(void* const* d_in, const int* in_sizes, int n_in,
                              void* d_out, int out_size, void* d_ws, size_t ws_size,
                              hipStream_t stream)
{
    (void)in_sizes; (void)n_in; (void)out_size; (void)ws_size;
    const float* img    = (const float*)d_in[0];
    const int*   toks   = (const int*)d_in[1];
    const float* qword  = (const float*)d_in[2];
    const float* Wih_f  = (const float*)d_in[3];
    const float* Whh_f  = (const float*)d_in[4];
    const float* bih_f  = (const float*)d_in[5];
    const float* bhh_f  = (const float*)d_in[6];
    const float* Wih_b  = (const float*)d_in[7];
    const float* Whh_b  = (const float*)d_in[8];
    const float* bih_b  = (const float*)d_in[9];
    const float* bhh_b  = (const float*)d_in[10];
    const float* proj_W = (const float*)d_in[11];
    const float* proj_b = (const float*)d_in[12];
    const float* vatt_vW = (const float*)d_in[13];
    const float* vatt_vb = (const float*)d_in[14];
    const float* vatt_qW = (const float*)d_in[15];
    const float* vatt_qb = (const float*)d_in[16];
    const float* vatt_oW = (const float*)d_in[17];
    /* d_in[18] vatt_ob: dropped (softmax shift-invariance) */
    const float* qnet_W = (const float*)d_in[19];
    const float* qnet_b = (const float*)d_in[20];
    const float* vnet_W = (const float*)d_in[21];
    const float* vnet_b = (const float*)d_in[22];
    const float* cls_W1 = (const float*)d_in[23];
    const float* cls_b1 = (const float*)d_in[24];
    const float* cls_W2 = (const float*)d_in[25];
    const float* cls_b2 = (const float*)d_in[26];
    const float* g0_W   = (const float*)d_in[27];
    const float* g0_b   = (const float*)d_in[28];
    const float* g1_W   = (const float*)d_in[29];
    const float* g1_b   = (const float*)d_in[30];
    const float* g2_W   = (const float*)d_in[31];
    const float* g2_b   = (const float*)d_in[32];
    const float* g3_W   = (const float*)d_in[33];
    const float* g3_b   = (const float*)d_in[34];
    const float* f0_W   = (const float*)d_in[35];
    const float* f0_b   = (const float*)d_in[36];
    const float* f1_W   = (const float*)d_in[37];
    const float* f1_b   = (const float*)d_in[38];

    float* out_logits = (float*)d_out;                  // [1536,2001]
    float* out_rec    = (float*)d_out + 1536 * 2001;    // [256,512]

    float* ws = (float*)d_ws;
    size_t off = 0;
    auto alloc = [&](size_t nf) { float* p = ws + off; off += nf; return p; };
    float* region0 = alloc((size_t)9216 * 512);  // gates [1536,2048] / hid1 [1536,1024] / gA [9216,512]
    float* h_f    = alloc((size_t)1536 * 512);
    float* h_b    = alloc((size_t)1536 * 512);
    float* cbuf   = alloc((size_t)1536 * 512);
    float* q_emb  = alloc((size_t)1536 * 512);
    float* q_proj = alloc((size_t)1536 * 512);
    float* v_emb  = alloc((size_t)1536 * 512);
    float* q_repr = alloc((size_t)1536 * 512);
    float* joint  = alloc((size_t)1536 * 512);
    float* Pb     = alloc((size_t)1536 * 512);
    float* Qb     = alloc((size_t)1536 * 512);
    float* gB     = alloc((size_t)9216 * 512);
    float* gsum_b = alloc((size_t)256 * 512);
    float* f0o    = alloc((size_t)256 * 512);
    float* rect   = alloc((size_t)256 * 512);
    float* swq    = alloc((size_t)1536 * 512);
    float* partial = alloc((size_t)75264 * 8);

    float* gates = region0;
    float* hid1  = region0;
    float* gA    = region0;

    auto gemm = [&](const float* A1, const int* idx1, int idxs, int lda1, int k1,
                    const float* W1, int ldw1,
                    const float* A2, int lda2, int k2, const float* W2, int ldw2,
                    const float* b1, const float* b2, const float* mulp,
                    float* Cp, int ldc, int M, int N, int relu, int mode) {
        dim3 g((N + BT - 1) / BT, (M + BT - 1) / BT);
        hipLaunchKernelGGL(mfma_gemm_kernel, g, dim3(256), 0, stream,
                           A1, idx1, idxs, lda1, k1, W1, ldw1, A2, lda2, k2, W2, ldw2,
                           b1, b2, mulp, Cp, ldc, M, N, relu, mode);
    };

    const int NR = 1536;
    // ---- bidirectional LSTM ----
    hipMemsetAsync(h_f, 0, (size_t)NR * 512 * sizeof(float), stream);
    hipMemsetAsync(cbuf, 0, (size_t)NR * 512 * sizeof(float), stream);
    for (int t = 0; t < 10; ++t) {
        gemm(qword, toks + t, 10, 300, 300, Wih_f, 300,
             h_f, 512, 512, Whh_f, 512,
             bih_f, bhh_f, nullptr, gates, 2048, NR, 2048, 0, 0);
        hipLaunchKernelGGL(lstm_cell_kernel, dim3(3072), dim3(256), 0, stream, gates, h_f, cbuf);
    }
    hipMemsetAsync(h_b, 0, (size_t)NR * 512 * sizeof(float), stream);
    hipMemsetAsync(cbuf, 0, (size_t)NR * 512 * sizeof(float), stream);
    for (int t = 0; t < 10; ++t) {
        gemm(qword, toks + (9 - t), 10, 300, 300, Wih_b, 300,
             h_b, 512, 512, Whh_b, 512,
             bih_b, bhh_b, nullptr, gates, 2048, NR, 2048, 0, 0);
        hipLaunchKernelGGL(lstm_cell_kernel, dim3(3072), dim3(256), 0, stream, gates, h_b, cbuf);
    }
    // q_emb = [h_f|h_b] @ proj_W^T + proj_b
    gemm(h_f, nullptr, 0, 512, 512, proj_W, 1024,
         h_b, 512, 512, proj_W + 512, 1024,
         proj_b, nullptr, nullptr, q_emb, 512, NR, 512, 0, 0);
    // q_proj = relu(q_emb @ vatt_qW^T + qb)
    gemm(q_emb, nullptr, 0, 512, 512, vatt_qW, 512,
         nullptr, 0, 0, nullptr, 0,
         vatt_qb, nullptr, nullptr, q_proj, 512, NR, 512, 1, 0);
    // attention: swq -> MFMA logits partials -> softmax + v_emb
    hipLaunchKernelGGL(swq_kernel, dim3(3072), dim3(256), 0, stream, q_proj, vatt_oW, swq);
    gemm(img, nullptr, 0, 512, 512, vatt_vW, 512,
         nullptr, 0, 0, nullptr, 0,
         vatt_vb, nullptr, swq, partial, 512, 75264, 512, 0, 1);
    hipLaunchKernelGGL(attn_vemb_kernel, dim3(1536), dim3(256), 0, stream,
                       partial, img, v_emb);
    // joint = relu(q_emb@qnet^T+b) * relu(v_emb@vnet^T+b)
    gemm(q_emb, nullptr, 0, 512, 512, qnet_W, 512, nullptr, 0, 0, nullptr, 0,
         qnet_b, nullptr, nullptr, q_repr, 512, NR, 512, 1, 0);
    gemm(v_emb, nullptr, 0, 512, 512, vnet_W, 512, nullptr, 0, 0, nullptr, 0,
         vnet_b, nullptr, q_repr, joint, 512, NR, 512, 1, 0);
    // classifier
    gemm(joint, nullptr, 0, 512, 512, cls_W1, 512, nullptr, 0, 0, nullptr, 0,
         cls_b1, nullptr, nullptr, hid1, 1024, NR, 1024, 1, 0);
    gemm(hid1, nullptr, 0, 1024, 1024, cls_W2, 1024, nullptr, 0, 0, nullptr, 0,
         cls_b2, nullptr, nullptr, out_logits, 2001, NR, 2001, 0, 0);
    // relation network: g0 factored via P (g0_W[:, :512]) and Q (g0_W[:, 512:])
    gemm(joint, nullptr, 0, 512, 512, g0_W, 1024, nullptr, 0, 0, nullptr, 0,
         nullptr, nullptr, nullptr, Pb, 512, NR, 512, 0, 0);
    gemm(joint, nullptr, 0, 512, 512, g0_W + 512, 1024, nullptr, 0, 0, nullptr, 0,
         nullptr, nullptr, nullptr, Qb, 512, NR, 512, 0, 0);
    hipLaunchKernelGGL(g0build_kernel, dim3(18432), dim3(256), 0, stream, Pb, Qb, g0_b, gA);
    gemm(gA, nullptr, 0, 512, 512, g1_W, 512, nullptr, 0, 0, nullptr, 0,
         g1_b, nullptr, nullptr, gB, 512, 9216, 512, 1, 0);
    gemm(gB, nullptr, 0, 512, 512, g2_W, 512, nullptr, 0, 0, nullptr, 0,
         g2_b, nullptr, nullptr, gA, 512, 9216, 512, 1, 0);
    gemm(gA, nullptr, 0, 512, 512, g3_W, 512, nullptr, 0, 0, nullptr, 0,
         g3_b, nullptr, nullptr, gB, 512, 9216, 512, 1, 0);
    hipLaunchKernelGGL(gsum_kernel, dim3(512), dim3(256), 0, stream, gB, gsum_b);
    gemm(gsum_b, nullptr, 0, 512, 512, f0_W, 512, nullptr, 0, 0, nullptr, 0,
         f0_b, nullptr, nullptr, f0o, 512, 256, 512, 1, 0);
    gemm(f0o, nullptr, 0, 512, 512, f1_W, 512, nullptr, 0, 0, nullptr, 0,
         f1_b, nullptr, nullptr, rect, 512, 256, 512, 0, 0);
    hipLaunchKernelGGL(l2norm_kernel, dim3(256), dim3(256), 0, stream, rect, out_rec);
}

// Round 4
// 1286.393 us; speedup vs baseline: 10.0612x; 1.0893x over previous
//
#include <hip/hip_runtime.h>
#include <hip/hip_bf16.h>
#include <math.h>

typedef __attribute__((ext_vector_type(8))) short short8;
typedef __attribute__((ext_vector_type(4))) float f32x4;

#define BT 64
#define KTILE 32
#define LSTR 40   // LDS row stride (bf16 elems)

__device__ __forceinline__ short8 cvt8(const float* x) {
    short8 r;
#pragma unroll
    for (int i = 0; i < 8; ++i) {
        __hip_bfloat16 b = __float2bfloat16(x[i]);
        r[i] = *reinterpret_cast<const short*>(&b);
    }
    return r;
}
__device__ __forceinline__ float bf2f(short s) {
    unsigned int u = ((unsigned int)(unsigned short)s) << 16;
    return __uint_as_float(u);
}

// ---------------- generic MFMA GEMM ----------------
// C[M,N] = concatK(A1|A2) @ concatK(W1|W2)^T (+bias1+bias2, relu, *mulvec[c], *mul[r,c])
// A1 rows optionally gathered via idx1. c_bf16: store bf16 bits into (short*)C.
__global__ __launch_bounds__(256)
void mfma_gemm_kernel(const float* __restrict__ A1, const int* __restrict__ idx1, int idx_stride,
                      int lda1, int k1,
                      const float* __restrict__ W1, int ldw1,
                      const float* __restrict__ A2, int lda2, int k2,
                      const float* __restrict__ W2, int ldw2,
                      const float* __restrict__ bias1, const float* __restrict__ bias2,
                      const float* __restrict__ mulvec, const float* __restrict__ mul,
                      float* __restrict__ C, int ldc, int M, int N, int do_relu, int c_bf16)
{
    __shared__ short sA[2][BT][LSTR];
    __shared__ short sB[2][BT][LSTR];

    const int tid = threadIdx.x;
    const int m0 = blockIdx.y * BT;
    const int n0 = blockIdx.x * BT;
    const int Ktot = k1 + k2;
    const int srow = tid >> 2;
    const int skq  = (tid & 3) << 3;
    const int lane = tid & 63;
    const int wave = tid >> 6;
    const int wr = (wave >> 1) << 5;
    const int wc = (wave & 1) << 5;
    const int l15 = lane & 15;
    const int lh  = lane >> 4;

    const int rg = min(m0 + srow, M - 1);
    const int arow = idx1 ? idx1[(size_t)rg * idx_stride] : rg;
    const int ng = min(n0 + srow, N - 1);

    f32x4 acc[2][2];
#pragma unroll
    for (int m = 0; m < 2; ++m)
#pragma unroll
        for (int n = 0; n < 2; ++n)
            acc[m][n] = (f32x4){0.f, 0.f, 0.f, 0.f};

    const int nt = (Ktot + KTILE - 1) / KTILE;
    float a[8], w[8];

    auto loadregs = [&](int t) {
        const int kb = t * KTILE;
        if (kb + KTILE <= k1) {
            const float* p = A1 + (size_t)arow * lda1 + kb + skq;
            float4 v0 = *(const float4*)p, v1 = *(const float4*)(p + 4);
            a[0]=v0.x; a[1]=v0.y; a[2]=v0.z; a[3]=v0.w; a[4]=v1.x; a[5]=v1.y; a[6]=v1.z; a[7]=v1.w;
            const float* q = W1 + (size_t)ng * ldw1 + kb + skq;
            float4 u0 = *(const float4*)q, u1 = *(const float4*)(q + 4);
            w[0]=u0.x; w[1]=u0.y; w[2]=u0.z; w[3]=u0.w; w[4]=u1.x; w[5]=u1.y; w[6]=u1.z; w[7]=u1.w;
        } else if (kb >= k1 && kb + KTILE <= Ktot) {
            const float* p = A2 + (size_t)rg * lda2 + (kb - k1) + skq;
            float4 v0 = *(const float4*)p, v1 = *(const float4*)(p + 4);
            a[0]=v0.x; a[1]=v0.y; a[2]=v0.z; a[3]=v0.w; a[4]=v1.x; a[5]=v1.y; a[6]=v1.z; a[7]=v1.w;
            const float* q = W2 + (size_t)ng * ldw2 + (kb - k1) + skq;
            float4 u0 = *(const float4*)q, u1 = *(const float4*)(q + 4);
            w[0]=u0.x; w[1]=u0.y; w[2]=u0.z; w[3]=u0.w; w[4]=u1.x; w[5]=u1.y; w[6]=u1.z; w[7]=u1.w;
        } else {
#pragma unroll
            for (int e = 0; e < 8; ++e) {
                int kg = kb + skq + e;
                float av = 0.f, wv = 0.f;
                if (kg < k1) {
                    av = A1[(size_t)arow * lda1 + kg];
                    wv = W1[(size_t)ng * ldw1 + kg];
                } else if (kg < Ktot) {
                    av = A2[(size_t)rg * lda2 + (kg - k1)];
                    wv = W2[(size_t)ng * ldw2 + (kg - k1)];
                }
                a[e] = av; w[e] = wv;
            }
        }
    };
    auto cvtwrite = [&](int buf) {
        *(short8*)&sA[buf][srow][skq] = cvt8(a);
        *(short8*)&sB[buf][srow][skq] = cvt8(w);
    };

    loadregs(0);
    cvtwrite(0);
    __syncthreads();

    for (int t = 0; t < nt; ++t) {
        const int cur = t & 1;
        if (t + 1 < nt) loadregs(t + 1);
        short8 af[2], bf[2];
#pragma unroll
        for (int m = 0; m < 2; ++m)
            af[m] = *(const short8*)&sA[cur][wr + (m << 4) + l15][lh << 3];
#pragma unroll
        for (int n = 0; n < 2; ++n)
            bf[n] = *(const short8*)&sB[cur][wc + (n << 4) + l15][lh << 3];
#pragma unroll
        for (int m = 0; m < 2; ++m)
#pragma unroll
            for (int n = 0; n < 2; ++n)
                acc[m][n] = __builtin_amdgcn_mfma_f32_16x16x32_bf16(af[m], bf[n], acc[m][n], 0, 0, 0);
        if (t + 1 < nt) cvtwrite(cur ^ 1);
        __syncthreads();
    }

#pragma unroll
    for (int m = 0; m < 2; ++m) {
#pragma unroll
        for (int j = 0; j < 4; ++j) {
            const int r = m0 + wr + (m << 4) + (lh << 2) + j;
            if (r >= M) continue;
#pragma unroll
            for (int n = 0; n < 2; ++n) {
                const int c = n0 + wc + (n << 4) + l15;
                if (c >= N) continue;
                float v = acc[m][n][j];
                if (bias1) v += bias1[c];
                if (bias2) v += bias2[c];
                if (do_relu) v = fmaxf(v, 0.f);
                if (mulvec) v *= mulvec[c];
                if (mul) v *= mul[(size_t)r * ldc + c];
                if (c_bf16) {
                    __hip_bfloat16 b = __float2bfloat16(v);
                    ((short*)C)[(size_t)r * ldc + c] = *(short*)&b;
                } else {
                    C[(size_t)r * ldc + c] = v;
                }
            }
        }
    }
}

// ---------------- LSTM weight reorder ----------------
// Permuted col c <-> unit u=c>>2, gate g=c&3 (src row g*512+u).
// Wbf [2048][832] bf16: cols 0..511 = Whh, 512..811 = Wih, 812..831 = 0.
// Wih_perm (fp32, may be null) [2048][300]. bias_perm[c] = bih[src]+bhh[src].
__global__ __launch_bounds__(256)
void lstm_reorder_kernel(const float* __restrict__ Wih, const float* __restrict__ Whh,
                         const float* __restrict__ bih, const float* __restrict__ bhh,
                         float* __restrict__ Wih_perm, short* __restrict__ Wbf,
                         float* __restrict__ bias_perm)
{
    int id = blockIdx.x * 256 + threadIdx.x;   // < 2048*512
    int c = id >> 9, k = id & 511;
    int src = (c & 3) * 512 + (c >> 2);
    {
        __hip_bfloat16 b = __float2bfloat16(Whh[(size_t)src * 512 + k]);
        Wbf[(size_t)c * 832 + k] = *(short*)&b;
    }
    if (k < 300) {
        float v = Wih[(size_t)src * 300 + k];
        if (Wih_perm) Wih_perm[(size_t)c * 300 + k] = v;
        __hip_bfloat16 b = __float2bfloat16(v);
        Wbf[(size_t)c * 832 + 512 + k] = *(short*)&b;
    } else if (k < 320) {
        Wbf[(size_t)c * 832 + 512 + k] = 0;
    }
    if (k == 0) bias_perm[c] = bih[src] + bhh[src];
}

// ---------------- fused LSTM step (GEMM + cell epilogue) ----------------
// gates_perm[r,c] = concat(h|emb) @ Wbf[c,:]^T + bias_perm[c] (+ xp[r,c])
// then cell update: lanes base..base+3 hold i,f,g,o of unit ccol>>2.
__global__ __launch_bounds__(256)
void lstm_step_kernel(const float* __restrict__ h_in, const short* __restrict__ Wbf,
                      const float* __restrict__ bias_perm,
                      const float* __restrict__ emb, const int* __restrict__ toks_t,
                      int k_emb, const short* __restrict__ xp,
                      float* __restrict__ h_out, float* __restrict__ cstate)
{
    __shared__ short sA[2][BT][LSTR];
    __shared__ short sB[2][BT][LSTR];
    const int tid = threadIdx.x;
    const int m0 = blockIdx.y << 6;
    const int n0 = blockIdx.x << 6;
    const int srow = tid >> 2, skq = (tid & 3) << 3;
    const int lane = tid & 63, wave = tid >> 6;
    const int wr = (wave >> 1) << 5, wc = (wave & 1) << 5;
    const int l15 = lane & 15, lh = lane >> 4;
    const int Ktot = 512 + k_emb;
    const int nt = (Ktot + 31) >> 5;
    const int rg = m0 + srow;
    const int ng = n0 + srow;
    const int arow = k_emb ? toks_t[rg * 10] : 0;

    f32x4 acc[2][2];
#pragma unroll
    for (int m = 0; m < 2; ++m)
#pragma unroll
        for (int n = 0; n < 2; ++n)
            acc[m][n] = (f32x4){0.f, 0.f, 0.f, 0.f};

    float a[8];
    short8 wb;
    auto loadregs = [&](int t) {
        const int kb = t << 5;
        wb = *(const short8*)&Wbf[(size_t)ng * 832 + kb + skq];
        const int k0 = kb + skq;
        if (k0 + 8 <= 512) {
            const float* p = h_in + ((size_t)rg << 9) + k0;
            float4 v0 = *(const float4*)p, v1 = *(const float4*)(p + 4);
            a[0]=v0.x; a[1]=v0.y; a[2]=v0.z; a[3]=v0.w; a[4]=v1.x; a[5]=v1.y; a[6]=v1.z; a[7]=v1.w;
        } else if (k0 + 8 <= Ktot) {   // k0 >= 512 guaranteed (k0 multiple of 8)
            const float* p = emb + (size_t)arow * 300 + (k0 - 512);
            float4 v0 = *(const float4*)p, v1 = *(const float4*)(p + 4);
            a[0]=v0.x; a[1]=v0.y; a[2]=v0.z; a[3]=v0.w; a[4]=v1.x; a[5]=v1.y; a[6]=v1.z; a[7]=v1.w;
        } else {
#pragma unroll
            for (int e = 0; e < 8; ++e) {
                int kg = k0 + e;
                a[e] = (kg < 512) ? h_in[((size_t)rg << 9) + kg]
                                  : (kg < Ktot ? emb[(size_t)arow * 300 + (kg - 512)] : 0.f);
            }
        }
    };
    auto cvtwrite = [&](int buf) {
        *(short8*)&sA[buf][srow][skq] = cvt8(a);
        *(short8*)&sB[buf][srow][skq] = wb;
    };

    loadregs(0);
    cvtwrite(0);
    __syncthreads();
    for (int t = 0; t < nt; ++t) {
        const int cur = t & 1;
        if (t + 1 < nt) loadregs(t + 1);
        short8 af[2], bf[2];
#pragma unroll
        for (int m = 0; m < 2; ++m)
            af[m] = *(const short8*)&sA[cur][wr + (m << 4) + l15][lh << 3];
#pragma unroll
        for (int n = 0; n < 2; ++n)
            bf[n] = *(const short8*)&sB[cur][wc + (n << 4) + l15][lh << 3];
#pragma unroll
        for (int m = 0; m < 2; ++m)
#pragma unroll
            for (int n = 0; n < 2; ++n)
                acc[m][n] = __builtin_amdgcn_mfma_f32_16x16x32_bf16(af[m], bf[n], acc[m][n], 0, 0, 0);
        if (t + 1 < nt) cvtwrite(cur ^ 1);
        __syncthreads();
    }

    // fused cell epilogue
#pragma unroll
    for (int n = 0; n < 2; ++n) {
        const int ccol = n0 + wc + (n << 4) + l15;
        const float bb = bias_perm[ccol];
        const int u = ccol >> 2;
#pragma unroll
        for (int m = 0; m < 2; ++m) {
#pragma unroll
            for (int j = 0; j < 4; ++j) {
                const int r = m0 + wr + (m << 4) + (lh << 2) + j;
                float v = acc[m][n][j] + bb;
                if (xp) v += bf2f(xp[(size_t)r * 20480 + ccol]);
                const int base = lane & ~3;
                float gi = __shfl(v, base, 64);
                float gf = __shfl(v, base | 1, 64);
                float gg = __shfl(v, base | 2, 64);
                float go = __shfl(v, base | 3, 64);
                if ((lane & 3) == 0) {
                    float si = 1.f / (1.f + expf(-gi));
                    float sf = 1.f / (1.f + expf(-gf));
                    float so = 1.f / (1.f + expf(-go));
                    size_t idx = ((size_t)r << 9) + u;
                    float cv = sf * cstate[idx] + si * tanhf(gg);
                    cstate[idx] = cv;
                    h_out[idx] = so * tanhf(cv);
                }
            }
        }
    }
}

// ---------------- attention logits (A-tile persistent in LDS) ----------------
// logits[m] = sum_h relu(img[m,:]·vW[h,:] + vb[h]) * swq[m/49, h]; M = 75264.
__global__ __launch_bounds__(256)
void attn_logits2_kernel(const float* __restrict__ img, const float* __restrict__ vW,
                         const float* __restrict__ vb, const float* __restrict__ swq,
                         float* __restrict__ logits)
{
    __shared__ short sA[64][520];      // 66.5 KB, row stride 1040 B (16B-mult, 2-way banks)
    __shared__ short sB[2][64][LSTR];
    __shared__ float sred[64][2];
    const int tid = threadIdx.x;
    const int m0 = blockIdx.x << 6;
    const int srow = tid >> 2, skq = (tid & 3) << 3;
    const int lane = tid & 63, wave = tid >> 6;
    const int wr = (wave >> 1) << 5, wc = (wave & 1) << 5;
    const int l15 = lane & 15, lh = lane >> 4;

    // stage full A tile (64 rows x 512 K) once
    for (int g = tid; g < 4096; g += 256) {
        int row = g >> 6, k8 = (g & 63) << 3;
        const float* p = img + (((size_t)(m0 + row)) << 9) + k8;
        float4 v0 = *(const float4*)p, v1 = *(const float4*)(p + 4);
        float tmp[8] = {v0.x, v0.y, v0.z, v0.w, v1.x, v1.y, v1.z, v1.w};
        *(short8*)&sA[row][k8] = cvt8(tmp);
    }

    float ps[2][4];
#pragma unroll
    for (int m = 0; m < 2; ++m)
#pragma unroll
        for (int j = 0; j < 4; ++j) ps[m][j] = 0.f;
    f32x4 acc[2][2];
#pragma unroll
    for (int m = 0; m < 2; ++m)
#pragma unroll
        for (int n = 0; n < 2; ++n) acc[m][n] = (f32x4){0.f, 0.f, 0.f, 0.f};

    float w[8];
    auto loadB = [&](int it) {
        const int nb = it >> 4, kb = (it & 15) << 5;
        const float* q = vW + (((size_t)(nb * 64 + srow)) << 9) + kb + skq;
        float4 u0 = *(const float4*)q, u1 = *(const float4*)(q + 4);
        w[0]=u0.x; w[1]=u0.y; w[2]=u0.z; w[3]=u0.w; w[4]=u1.x; w[5]=u1.y; w[6]=u1.z; w[7]=u1.w;
    };
    loadB(0);
    *(short8*)&sB[0][srow][skq] = cvt8(w);
    __syncthreads();

    for (int it = 0; it < 128; ++it) {
        const int cur = it & 1;
        if (it + 1 < 128) loadB(it + 1);
        const int kc = (it & 15) << 5;
        short8 af[2], bf[2];
        af[0] = *(const short8*)&sA[wr + l15][kc + (lh << 3)];
        af[1] = *(const short8*)&sA[wr + 16 + l15][kc + (lh << 3)];
        bf[0] = *(const short8*)&sB[cur][wc + l15][lh << 3];
        bf[1] = *(const short8*)&sB[cur][wc + 16 + l15][lh << 3];
#pragma unroll
        for (int m = 0; m < 2; ++m)
#pragma unroll
            for (int n = 0; n < 2; ++n)
                acc[m][n] = __builtin_amdgcn_mfma_f32_16x16x32_bf16(af[m], bf[n], acc[m][n], 0, 0, 0);
        if ((it & 15) == 15) {
            const int nb = it >> 4;
#pragma unroll
            for (int m = 0; m < 2; ++m) {
#pragma unroll
                for (int j = 0; j < 4; ++j) {
                    const int r = m0 + wr + (m << 4) + (lh << 2) + j;
                    const float* sq = swq + (size_t)(r / 49) * 512 + (nb << 6);
                    float s = 0.f;
#pragma unroll
                    for (int n = 0; n < 2; ++n) {
                        const int cl = wc + (n << 4) + l15;
                        float v = acc[m][n][j] + vb[(nb << 6) + cl];
                        v = fmaxf(v, 0.f);
                        s += v * sq[cl];
                    }
                    s += __shfl_xor(s, 1, 64);
                    s += __shfl_xor(s, 2, 64);
                    s += __shfl_xor(s, 4, 64);
                    s += __shfl_xor(s, 8, 64);
                    ps[m][j] += s;
                }
            }
#pragma unroll
            for (int m = 0; m < 2; ++m)
#pragma unroll
                for (int n = 0; n < 2; ++n) acc[m][n] = (f32x4){0.f, 0.f, 0.f, 0.f};
        }
        if (it + 1 < 128) *(short8*)&sB[cur ^ 1][srow][skq] = cvt8(w);
        __syncthreads();
    }
#pragma unroll
    for (int m = 0; m < 2; ++m)
#pragma unroll
        for (int j = 0; j < 4; ++j)
            if (l15 == 0) sred[wr + (m << 4) + (lh << 2) + j][wc >> 5] = ps[m][j];
    __syncthreads();
    if (tid < 64) logits[(size_t)(m0 + tid)] = sred[tid][0] + sred[tid][1];
}

// softmax over 49 per n, then v_emb[n,h] = sum_k att[k]*img[n,k,h]
__global__ __launch_bounds__(256)
void attn_vemb_kernel(const float* __restrict__ logits, const float* __restrict__ img,
                      float* __restrict__ v_emb)
{
    __shared__ float satt[49];
    const int n = blockIdx.x;
    const int tid = threadIdx.x;
    if (tid < 64) {
        float v = (tid < 49) ? logits[(size_t)n * 49 + tid] : -1e30f;
        float m = v;
#pragma unroll
        for (int off = 32; off; off >>= 1) m = fmaxf(m, __shfl_xor(m, off, 64));
        float e = (tid < 49) ? expf(v - m) : 0.f;
        float s = e;
#pragma unroll
        for (int off = 32; off; off >>= 1) s += __shfl_xor(s, off, 64);
        if (tid < 49) satt[tid] = e / s;
    }
    __syncthreads();
    const float2* ip = (const float2*)(img + (size_t)n * 49 * 512);
    float2 s2 = make_float2(0.f, 0.f);
    for (int k = 0; k < 49; ++k) {
        float2 v = ip[k * 256 + tid];
        float a = satt[k];
        s2.x = fmaf(a, v.x, s2.x);
        s2.y = fmaf(a, v.y, s2.y);
    }
    ((float2*)(v_emb + (size_t)n * 512))[tid] = s2;
}

__global__ __launch_bounds__(256)
void g0build_kernel(const float* __restrict__ P, const float* __restrict__ Q,
                    const float* __restrict__ b0, float* __restrict__ g0)
{
    int id = blockIdx.x * 256 + threadIdx.x;   // < 9216*512
    int cc = id & 511;
    int r = id >> 9;
    int j = r % 6;
    int t = r / 6;
    int i = t % 6;
    int b = t / 6;
    float v = P[((size_t)(b * 6 + j) << 9) + cc] + Q[((size_t)(b * 6 + i) << 9) + cc] + b0[cc];
    g0[id] = fmaxf(v, 0.f);
}

__global__ __launch_bounds__(256)
void gsum_kernel(const float* __restrict__ g, float* __restrict__ out)
{
    int id = blockIdx.x * 256 + threadIdx.x;   // < 256*512
    int b = id >> 9, hh = id & 511;
    const float* p = g + (size_t)b * 36 * 512 + hh;
    float s = 0.f;
#pragma unroll
    for (int i = 0; i < 36; ++i) s += p[i * 512];
    out[id] = s;
}

__global__ __launch_bounds__(256)
void l2norm_kernel(const float* __restrict__ in, float* __restrict__ out)
{
    int b = blockIdx.x;
    int tid = threadIdx.x;
    float v0 = in[(size_t)b * 512 + tid];
    float v1 = in[(size_t)b * 512 + 256 + tid];
    float s = v0 * v0 + v1 * v1;
#pragma unroll
    for (int off = 32; off; off >>= 1) s += __shfl_down(s, off, 64);
    __shared__ float ps[4];
    if ((tid & 63) == 0) ps[tid >> 6] = s;
    __syncthreads();
    float tot = ps[0] + ps[1] + ps[2] + ps[3];
    float inv = 1.f / sqrtf(tot);
    out[(size_t)b * 512 + tid] = v0 * inv;
    out[(size_t)b * 512 + 256 + tid] = v1 * inv;
}

extern "C" void kernel_launch(void* const* d_in, const int* in_sizes, int n_in,
                              void* d_out, int out_size, void* d_ws, size_t ws_size,
                              hipStream_t stream)
{
    (void)in_sizes; (void)n_in; (void)out_size;
    const float* img    = (const float*)d_in[0];
    const int*   toks   = (const int*)d_in[1];
    const float* qword  = (const float*)d_in[2];
    const float* Wih_f  = (const float*)d_in[3];
    const float* Whh_f  = (const float*)d_in[4];
    const float* bih_f  = (const float*)d_in[5];
    const float* bhh_f  = (const float*)d_in[6];
    const float* Wih_b  = (const float*)d_in[7];
    const float* Whh_b  = (const float*)d_in[8];
    const float* bih_b  = (const float*)d_in[9];
    const float* bhh_b  = (const float*)d_in[10];
    const float* proj_W = (const float*)d_in[11];
    const float* proj_b = (const float*)d_in[12];
    const float* vatt_vW = (const float*)d_in[13];
    const float* vatt_vb = (const float*)d_in[14];
    const float* vatt_qW = (const float*)d_in[15];
    const float* vatt_qb = (const float*)d_in[16];
    const float* vatt_oW = (const float*)d_in[17];
    const float* qnet_W = (const float*)d_in[19];
    const float* qnet_b = (const float*)d_in[20];
    const float* vnet_W = (const float*)d_in[21];
    const float* vnet_b = (const float*)d_in[22];
    const float* cls_W1 = (const float*)d_in[23];
    const float* cls_b1 = (const float*)d_in[24];
    const float* cls_W2 = (const float*)d_in[25];
    const float* cls_b2 = (const float*)d_in[26];
    const float* g0_W   = (const float*)d_in[27];
    const float* g0_b   = (const float*)d_in[28];
    const float* g1_W   = (const float*)d_in[29];
    const float* g1_b   = (const float*)d_in[30];
    const float* g2_W   = (const float*)d_in[31];
    const float* g2_b   = (const float*)d_in[32];
    const float* g3_W   = (const float*)d_in[33];
    const float* g3_b   = (const float*)d_in[34];
    const float* f0_W   = (const float*)d_in[35];
    const float* f0_b   = (const float*)d_in[36];
    const float* f1_W   = (const float*)d_in[37];
    const float* f1_b   = (const float*)d_in[38];

    float* out_logits = (float*)d_out;                  // [1536,2001]
    float* out_rec    = (float*)d_out + 1536 * 2001;    // [256,512]

    const size_t FB = 786432;  // 1536*512
    float* zone = (float*)d_ws;
    // late-phase buffers (alias xproj region; only used after LSTM)
    float* gA    = zone;                        // 4718592
    float* gB    = zone + 4718592;              // 4718592
    float* hid1  = zone + 9437184;              // 1572864
    float* Pb    = zone + 11010048;             // 786432
    float* Qb    = zone + 11796480;             // 786432
    float* gsumb = zone + 12582912;             // 131072
    float* f0o   = zone + 12713984;             // 131072
    float* rectb = zone + 12845056;             // 131072
    // aliases (dead before their hosts are written)
    float* q_emb  = Pb;          // dead after qnet (before P-GEMM)
    float* swq    = hid1;        // dead after attn logits (before cls1)
    float* q_repr = gA;          // dead after vnet (before g0build)
    float* v_emb  = gA + FB;     // dead after vnet

    const size_t ZEXT_H = 31457280;   // 2 x 15360*2048 bf16 (in float units)
    const size_t ZEXT_F = 12976128;
    const size_t PERS   = 4 * FB + FB + FB + 75264 + 2 * 851968 + 2 * 2048;
    const size_t NEED_H = (ZEXT_H + PERS + 2 * 614400) * 4;
    const bool hoisted = ws_size >= NEED_H;

    short* xprojF = (short*)zone;                   // [15360][2048] bf16
    short* xprojB = (short*)zone + ZEXT_H;          // second half of zone (shorts)

    float* p = zone + (hoisted ? ZEXT_H : ZEXT_F);
    auto alloc = [&](size_t nf) { float* q = p; p += nf; return q; };
    float* hP0  = alloc(FB);
    float* hP1  = alloc(FB);
    float* hP2  = alloc(FB);
    float* hP3  = alloc(FB);
    float* cbuf = alloc(FB);
    float* joint = alloc(FB);
    float* logit49 = alloc(75264);
    short* WbfF = (short*)alloc(851968);   // [2048][832] bf16
    short* WbfB = (short*)alloc(851968);
    float* biasF = alloc(2048);
    float* biasB = alloc(2048);
    float* WihpF = nullptr;
    float* WihpB = nullptr;
    if (hoisted) { WihpF = alloc(614400); WihpB = alloc(614400); }

    auto gemm = [&](const float* A1, const int* idx1, int idxs, int lda1, int k1,
                    const float* W1, int ldw1,
                    const float* A2, int lda2, int k2, const float* W2, int ldw2,
                    const float* b1, const float* b2, const float* mv, const float* mulp,
                    float* Cp, int ldc, int M, int N, int relu, int cbf) {
        dim3 g((N + BT - 1) / BT, (M + BT - 1) / BT);
        hipLaunchKernelGGL(mfma_gemm_kernel, g, dim3(256), 0, stream,
                           A1, idx1, idxs, lda1, k1, W1, ldw1, A2, lda2, k2, W2, ldw2,
                           b1, b2, mv, mulp, Cp, ldc, M, N, relu, cbf);
    };

    const int NR = 1536;
    // ---- weight reorders ----
    hipLaunchKernelGGL(lstm_reorder_kernel, dim3(4096), dim3(256), 0, stream,
                       Wih_f, Whh_f, bih_f, bhh_f, WihpF, WbfF, biasF);
    hipLaunchKernelGGL(lstm_reorder_kernel, dim3(4096), dim3(256), 0, stream,
                       Wih_b, Whh_b, bih_b, bhh_b, WihpB, WbfB, biasB);
    // ---- hoisted input projections (bf16 outputs) ----
    if (hoisted) {
        gemm(qword, toks, 1, 300, 300, WihpF, 300, nullptr, 0, 0, nullptr, 0,
             nullptr, nullptr, nullptr, nullptr, (float*)xprojF, 2048, 15360, 2048, 0, 1);
        gemm(qword, toks, 1, 300, 300, WihpB, 300, nullptr, 0, 0, nullptr, 0,
             nullptr, nullptr, nullptr, nullptr, (float*)xprojB, 2048, 15360, 2048, 0, 1);
    }
    // ---- bidirectional LSTM (fused cell) ----
    dim3 sg(32, 24);
    hipMemsetAsync(hP0, 0, FB * sizeof(float), stream);
    hipMemsetAsync(cbuf, 0, FB * sizeof(float), stream);
    {
        float* hi = hP0; float* ho = hP1;
        for (int t = 0; t < 10; ++t) {
            if (hoisted)
                hipLaunchKernelGGL(lstm_step_kernel, sg, dim3(256), 0, stream,
                                   hi, WbfF, biasF, nullptr, nullptr, 0,
                                   xprojF + (size_t)t * 2048, ho, cbuf);
            else
                hipLaunchKernelGGL(lstm_step_kernel, sg, dim3(256), 0, stream,
                                   hi, WbfF, biasF, qword, toks + t, 300,
                                   (const short*)nullptr, ho, cbuf);
            float* tmp = hi; hi = ho; ho = tmp;
        }
    }   // final h_f in hP0
    hipMemsetAsync(hP2, 0, FB * sizeof(float), stream);
    hipMemsetAsync(cbuf, 0, FB * sizeof(float), stream);
    {
        float* hi = hP2; float* ho = hP3;
        for (int s = 0; s < 10; ++s) {
            int t = 9 - s;
            if (hoisted)
                hipLaunchKernelGGL(lstm_step_kernel, sg, dim3(256), 0, stream,
                                   hi, WbfB, biasB, nullptr, nullptr, 0,
                                   xprojB + (size_t)t * 2048, ho, cbuf);
            else
                hipLaunchKernelGGL(lstm_step_kernel, sg, dim3(256), 0, stream,
                                   hi, WbfB, biasB, qword, toks + t, 300,
                                   (const short*)nullptr, ho, cbuf);
            float* tmp = hi; hi = ho; ho = tmp;
        }
    }   // final h_b in hP2

    // q_emb = [h_f|h_b] @ proj_W^T + proj_b
    gemm(hP0, nullptr, 0, 512, 512, proj_W, 1024,
         hP2, 512, 512, proj_W + 512, 1024,
         proj_b, nullptr, nullptr, nullptr, q_emb, 512, NR, 512, 0, 0);
    // swq = relu(q_emb @ qW^T + qb) * oW   (fused)
    gemm(q_emb, nullptr, 0, 512, 512, vatt_qW, 512, nullptr, 0, 0, nullptr, 0,
         vatt_qb, nullptr, vatt_oW, nullptr, swq, 512, NR, 512, 1, 0);
    // attention logits + softmax/v_emb
    hipLaunchKernelGGL(attn_logits2_kernel, dim3(1176), dim3(256), 0, stream,
                       img, vatt_vW, vatt_vb, swq, logit49);
    hipLaunchKernelGGL(attn_vemb_kernel, dim3(1536), dim3(256), 0, stream,
                       logit49, img, v_emb);
    // joint = relu(q_emb@qnet^T+b) * relu(v_emb@vnet^T+b)
    gemm(q_emb, nullptr, 0, 512, 512, qnet_W, 512, nullptr, 0, 0, nullptr, 0,
         qnet_b, nullptr, nullptr, nullptr, q_repr, 512, NR, 512, 1, 0);
    gemm(v_emb, nullptr, 0, 512, 512, vnet_W, 512, nullptr, 0, 0, nullptr, 0,
         vnet_b, nullptr, nullptr, q_repr, joint, 512, NR, 512, 1, 0);
    // classifier
    gemm(joint, nullptr, 0, 512, 512, cls_W1, 512, nullptr, 0, 0, nullptr, 0,
         cls_b1, nullptr, nullptr, nullptr, hid1, 1024, NR, 1024, 1, 0);
    gemm(hid1, nullptr, 0, 1024, 1024, cls_W2, 1024, nullptr, 0, 0, nullptr, 0,
         cls_b2, nullptr, nullptr, nullptr, out_logits, 2001, NR, 2001, 0, 0);
    // relation network
    gemm(joint, nullptr, 0, 512, 512, g0_W, 1024, nullptr, 0, 0, nullptr, 0,
         nullptr, nullptr, nullptr, nullptr, Pb, 512, NR, 512, 0, 0);
    gemm(joint, nullptr, 0, 512, 512, g0_W + 512, 1024, nullptr, 0, 0, nullptr, 0,
         nullptr, nullptr, nullptr, nullptr, Qb, 512, NR, 512, 0, 0);
    hipLaunchKernelGGL(g0build_kernel, dim3(18432), dim3(256), 0, stream, Pb, Qb, g0_b, gA);
    gemm(gA, nullptr, 0, 512, 512, g1_W, 512, nullptr, 0, 0, nullptr, 0,
         g1_b, nullptr, nullptr, nullptr, gB, 512, 9216, 512, 1, 0);
    gemm(gB, nullptr, 0, 512, 512, g2_W, 512, nullptr, 0, 0, nullptr, 0,
         g2_b, nullptr, nullptr, nullptr, gA, 512, 9216, 512, 1, 0);
    gemm(gA, nullptr, 0, 512, 512, g3_W, 512, nullptr, 0, 0, nullptr, 0,
         g3_b, nullptr, nullptr, nullptr, gB, 512, 9216, 512, 1, 0);
    hipLaunchKernelGGL(gsum_kernel, dim3(512), dim3(256), 0, stream, gB, gsumb);
    gemm(gsumb, nullptr, 0, 512, 512, f0_W, 512, nullptr, 0, 0, nullptr, 0,
         f0_b, nullptr, nullptr, nullptr, f0o, 512, 256, 512, 1, 0);
    gemm(f0o, nullptr, 0, 512, 512, f1_W, 512, nullptr, 0, 0, nullptr, 0,
         f1_b, nullptr, nullptr, nullptr, rectb, 512, 256, 512, 0, 0);
    hipLaunchKernelGGL(l2norm_kernel, dim3(256), dim3(256), 0, stream, rectb, out_rec);
}

// Round 6
// 941.626 us; speedup vs baseline: 13.7451x; 1.3661x over previous
//
#include <hip/hip_runtime.h>
#include <hip/hip_bf16.h>
#include <math.h>

typedef __attribute__((ext_vector_type(8))) short short8;
typedef __attribute__((ext_vector_type(4))) float f32x4;

#define BT 64
#define KTILE 32
#define LSTR 40   // LDS row stride (bf16 elems): 80 B -> 2-way bank aliasing (free)

__device__ __forceinline__ short8 cvt8(const float* x) {
    short8 r;
#pragma unroll
    for (int i = 0; i < 8; ++i) {
        __hip_bfloat16 b = __float2bfloat16(x[i]);
        r[i] = *reinterpret_cast<const short*>(&b);
    }
    return r;
}

// ---------------- generic MFMA GEMM ----------------
// C[M,N] = concatK(A1|A2) @ concatK(W1|W2)^T (+bias1+bias2, relu, *mulvec[c], *mul[r,c])
// A1 rows optionally gathered via idx1.
// mode 0: 2D grid, store C.
// mode 1 (attn logits): 1D XCD-swizzled grid (9408 blocks, M=75264, N=512);
//   per-row reduce of relu(acc+bias1[c])*mul[(r/49)*ldc+c] -> C[r*8+chunk].
__global__ __launch_bounds__(256)
void mfma_gemm_kernel(const float* __restrict__ A1, const int* __restrict__ idx1, int idx_stride,
                      int lda1, int k1,
                      const float* __restrict__ W1, int ldw1,
                      const float* __restrict__ A2, int lda2, int k2,
                      const float* __restrict__ W2, int ldw2,
                      const float* __restrict__ bias1, const float* __restrict__ bias2,
                      const float* __restrict__ mulvec, const float* __restrict__ mul,
                      float* __restrict__ C, int ldc, int M, int N, int do_relu, int mode)
{
    __shared__ short sA[2][BT][LSTR];
    __shared__ short sB[2][BT][LSTR];
    __shared__ float sred[BT][2];

    const int tid = threadIdx.x;
    int m0, n0, ch8 = 0;
    if (mode == 1) {
        const int xcd = blockIdx.x & 7;
        const int gi = xcd * 1176 + (blockIdx.x >> 3);
        m0 = (gi >> 3) << 6;
        ch8 = gi & 7;
        n0 = ch8 << 6;
    } else {
        m0 = blockIdx.y * BT;
        n0 = blockIdx.x * BT;
    }
    const int Ktot = k1 + k2;
    const int srow = tid >> 2;
    const int skq  = (tid & 3) << 3;
    const int lane = tid & 63;
    const int wave = tid >> 6;
    const int wr = (wave >> 1) << 5;
    const int wc = (wave & 1) << 5;
    const int l15 = lane & 15;
    const int lh  = lane >> 4;

    const int rg = min(m0 + srow, M - 1);
    const int arow = idx1 ? idx1[(size_t)rg * idx_stride] : rg;
    const int ng = min(n0 + srow, N - 1);

    f32x4 acc[2][2];
#pragma unroll
    for (int m = 0; m < 2; ++m)
#pragma unroll
        for (int n = 0; n < 2; ++n)
            acc[m][n] = (f32x4){0.f, 0.f, 0.f, 0.f};

    const int nt = (Ktot + KTILE - 1) / KTILE;
    float a[8], w[8];

    auto loadregs = [&](int t) {
        const int kb = t * KTILE;
        if (kb + KTILE <= k1) {
            const float* p = A1 + (size_t)arow * lda1 + kb + skq;
            float4 v0 = *(const float4*)p, v1 = *(const float4*)(p + 4);
            a[0]=v0.x; a[1]=v0.y; a[2]=v0.z; a[3]=v0.w; a[4]=v1.x; a[5]=v1.y; a[6]=v1.z; a[7]=v1.w;
            const float* q = W1 + (size_t)ng * ldw1 + kb + skq;
            float4 u0 = *(const float4*)q, u1 = *(const float4*)(q + 4);
            w[0]=u0.x; w[1]=u0.y; w[2]=u0.z; w[3]=u0.w; w[4]=u1.x; w[5]=u1.y; w[6]=u1.z; w[7]=u1.w;
        } else if (kb >= k1 && kb + KTILE <= Ktot) {
            const float* p = A2 + (size_t)rg * lda2 + (kb - k1) + skq;
            float4 v0 = *(const float4*)p, v1 = *(const float4*)(p + 4);
            a[0]=v0.x; a[1]=v0.y; a[2]=v0.z; a[3]=v0.w; a[4]=v1.x; a[5]=v1.y; a[6]=v1.z; a[7]=v1.w;
            const float* q = W2 + (size_t)ng * ldw2 + (kb - k1) + skq;
            float4 u0 = *(const float4*)q, u1 = *(const float4*)(q + 4);
            w[0]=u0.x; w[1]=u0.y; w[2]=u0.z; w[3]=u0.w; w[4]=u1.x; w[5]=u1.y; w[6]=u1.z; w[7]=u1.w;
        } else {
#pragma unroll
            for (int e = 0; e < 8; ++e) {
                int kg = kb + skq + e;
                float av = 0.f, wv = 0.f;
                if (kg < k1) {
                    av = A1[(size_t)arow * lda1 + kg];
                    wv = W1[(size_t)ng * ldw1 + kg];
                } else if (kg < Ktot) {
                    av = A2[(size_t)rg * lda2 + (kg - k1)];
                    wv = W2[(size_t)ng * ldw2 + (kg - k1)];
                }
                a[e] = av; w[e] = wv;
            }
        }
    };
    auto cvtwrite = [&](int buf) {
        *(short8*)&sA[buf][srow][skq] = cvt8(a);
        *(short8*)&sB[buf][srow][skq] = cvt8(w);
    };

    loadregs(0);
    cvtwrite(0);
    __syncthreads();

    for (int t = 0; t < nt; ++t) {
        const int cur = t & 1;
        if (t + 1 < nt) loadregs(t + 1);
        short8 af[2], bf[2];
#pragma unroll
        for (int m = 0; m < 2; ++m)
            af[m] = *(const short8*)&sA[cur][wr + (m << 4) + l15][lh << 3];
#pragma unroll
        for (int n = 0; n < 2; ++n)
            bf[n] = *(const short8*)&sB[cur][wc + (n << 4) + l15][lh << 3];
#pragma unroll
        for (int m = 0; m < 2; ++m)
#pragma unroll
            for (int n = 0; n < 2; ++n)
                acc[m][n] = __builtin_amdgcn_mfma_f32_16x16x32_bf16(af[m], bf[n], acc[m][n], 0, 0, 0);
        if (t + 1 < nt) cvtwrite(cur ^ 1);
        __syncthreads();
    }

    if (mode == 0) {
#pragma unroll
        for (int m = 0; m < 2; ++m) {
#pragma unroll
            for (int j = 0; j < 4; ++j) {
                const int r = m0 + wr + (m << 4) + (lh << 2) + j;
                if (r >= M) continue;
#pragma unroll
                for (int n = 0; n < 2; ++n) {
                    const int c = n0 + wc + (n << 4) + l15;
                    if (c >= N) continue;
                    float v = acc[m][n][j];
                    if (bias1) v += bias1[c];
                    if (bias2) v += bias2[c];
                    if (do_relu) v = fmaxf(v, 0.f);
                    if (mulvec) v *= mulvec[c];
                    if (mul) v *= mul[(size_t)r * ldc + c];
                    C[(size_t)r * ldc + c] = v;
                }
            }
        }
    } else {
        // attention col-reduce epilogue: bias1 = vb, mul = swq (stride ldc)
#pragma unroll
        for (int m = 0; m < 2; ++m) {
#pragma unroll
            for (int j = 0; j < 4; ++j) {
                const int rloc = wr + (m << 4) + (lh << 2) + j;
                const int r = m0 + rloc;
                const size_t sqbase = (size_t)(r / 49) * ldc;
                float s = 0.f;
#pragma unroll
                for (int n = 0; n < 2; ++n) {
                    const int c = n0 + wc + (n << 4) + l15;
                    float v = acc[m][n][j] + bias1[c];
                    v = fmaxf(v, 0.f);
                    s += v * mul[sqbase + c];
                }
                s += __shfl_xor(s, 1, 64);
                s += __shfl_xor(s, 2, 64);
                s += __shfl_xor(s, 4, 64);
                s += __shfl_xor(s, 8, 64);
                if (l15 == 0) sred[rloc][wc >> 5] = s;
            }
        }
        __syncthreads();
        if (tid < BT)
            C[(size_t)(m0 + tid) * 8 + ch8] = sred[tid][0] + sred[tid][1];
    }
}

// ---------------- LSTM weight reorder ----------------
// Permuted col c <-> unit u=c>>2, gate g=c&3 (src row g*512+u).
// Wbf [2048][832] bf16: cols 0..511 = Whh, 512..811 = Wih, 812..831 = 0.
// bias_perm[c] = bih[src]+bhh[src].
__global__ __launch_bounds__(256)
void lstm_reorder_kernel(const float* __restrict__ Wih, const float* __restrict__ Whh,
                         const float* __restrict__ bih, const float* __restrict__ bhh,
                         short* __restrict__ Wbf, float* __restrict__ bias_perm)
{
    int id = blockIdx.x * 256 + threadIdx.x;   // < 2048*512
    int c = id >> 9, k = id & 511;
    int src = (c & 3) * 512 + (c >> 2);
    {
        __hip_bfloat16 b = __float2bfloat16(Whh[(size_t)src * 512 + k]);
        Wbf[(size_t)c * 832 + k] = *(short*)&b;
    }
    if (k < 300) {
        __hip_bfloat16 b = __float2bfloat16(Wih[(size_t)src * 300 + k]);
        Wbf[(size_t)c * 832 + 512 + k] = *(short*)&b;
    } else if (k < 320) {
        Wbf[(size_t)c * 832 + 512 + k] = 0;
    }
    if (k == 0) bias_perm[c] = bih[src] + bhh[src];
}

// ---------------- fused LSTM step, both directions (GEMM + cell epilogue) ----------------
// blockIdx.z: 0 = forward (time tF), 1 = backward (time tB).
// gates_perm[r,c] = concat(h|emb[tok]) @ Wbf[c,:]^T + bias_perm[c]; cell update fused.
__global__ __launch_bounds__(256)
void lstm_step2_kernel(const float* __restrict__ hF_in, const float* __restrict__ hB_in,
                       const short* __restrict__ WbfF, const short* __restrict__ WbfB,
                       const float* __restrict__ biasF, const float* __restrict__ biasB,
                       const float* __restrict__ emb, const int* __restrict__ toks,
                       int tF, int tB,
                       float* __restrict__ hF_out, float* __restrict__ hB_out,
                       float* __restrict__ cF, float* __restrict__ cB)
{
    __shared__ short sA[2][BT][LSTR];
    __shared__ short sB[2][BT][LSTR];
    const int dir = blockIdx.z;
    const float* h_in = dir ? hB_in : hF_in;
    const short* Wbf  = dir ? WbfB : WbfF;
    const float* bias_perm = dir ? biasB : biasF;
    float* h_out  = dir ? hB_out : hF_out;
    float* cstate = dir ? cB : cF;
    const int tt = dir ? tB : tF;

    const int tid = threadIdx.x;
    const int m0 = blockIdx.y << 6;
    const int n0 = blockIdx.x << 6;
    const int srow = tid >> 2, skq = (tid & 3) << 3;
    const int lane = tid & 63, wave = tid >> 6;
    const int wr = (wave >> 1) << 5, wc = (wave & 1) << 5;
    const int l15 = lane & 15, lh = lane >> 4;
    const int Ktot = 812;
    const int nt = 26;                    // 26*32 = 832 (zero-padded)
    const int rg = m0 + srow;
    const int ng = n0 + srow;
    const int arow = toks[rg * 10 + tt];

    f32x4 acc[2][2];
#pragma unroll
    for (int m = 0; m < 2; ++m)
#pragma unroll
        for (int n = 0; n < 2; ++n)
            acc[m][n] = (f32x4){0.f, 0.f, 0.f, 0.f};

    float a[8];
    short8 wb;
    auto loadregs = [&](int t) {
        const int kb = t << 5;
        wb = *(const short8*)&Wbf[(size_t)ng * 832 + kb + skq];
        const int k0 = kb + skq;
        if (k0 + 8 <= 512) {
            const float* p = h_in + ((size_t)rg << 9) + k0;
            float4 v0 = *(const float4*)p, v1 = *(const float4*)(p + 4);
            a[0]=v0.x; a[1]=v0.y; a[2]=v0.z; a[3]=v0.w; a[4]=v1.x; a[5]=v1.y; a[6]=v1.z; a[7]=v1.w;
        } else if (k0 + 8 <= Ktot) {   // k0 >= 512 (k0 multiple of 8)
            const float* p = emb + (size_t)arow * 300 + (k0 - 512);
            float4 v0 = *(const float4*)p, v1 = *(const float4*)(p + 4);
            a[0]=v0.x; a[1]=v0.y; a[2]=v0.z; a[3]=v0.w; a[4]=v1.x; a[5]=v1.y; a[6]=v1.z; a[7]=v1.w;
        } else {
#pragma unroll
            for (int e = 0; e < 8; ++e) {
                int kg = k0 + e;
                a[e] = (kg < 512) ? h_in[((size_t)rg << 9) + kg]
                                  : (kg < Ktot ? emb[(size_t)arow * 300 + (kg - 512)] : 0.f);
            }
        }
    };
    auto cvtwrite = [&](int buf) {
        *(short8*)&sA[buf][srow][skq] = cvt8(a);
        *(short8*)&sB[buf][srow][skq] = wb;
    };

    loadregs(0);
    cvtwrite(0);
    __syncthreads();
    for (int t = 0; t < nt; ++t) {
        const int cur = t & 1;
        if (t + 1 < nt) loadregs(t + 1);
        short8 af[2], bf[2];
#pragma unroll
        for (int m = 0; m < 2; ++m)
            af[m] = *(const short8*)&sA[cur][wr + (m << 4) + l15][lh << 3];
#pragma unroll
        for (int n = 0; n < 2; ++n)
            bf[n] = *(const short8*)&sB[cur][wc + (n << 4) + l15][lh << 3];
#pragma unroll
        for (int m = 0; m < 2; ++m)
#pragma unroll
            for (int n = 0; n < 2; ++n)
                acc[m][n] = __builtin_amdgcn_mfma_f32_16x16x32_bf16(af[m], bf[n], acc[m][n], 0, 0, 0);
        if (t + 1 < nt) cvtwrite(cur ^ 1);
        __syncthreads();
    }

    // fused cell epilogue: lanes base..base+3 hold i,f,g,o of unit ccol>>2
#pragma unroll
    for (int n = 0; n < 2; ++n) {
        const int ccol = n0 + wc + (n << 4) + l15;
        const float bb = bias_perm[ccol];
        const int u = ccol >> 2;
#pragma unroll
        for (int m = 0; m < 2; ++m) {
#pragma unroll
            for (int j = 0; j < 4; ++j) {
                const int r = m0 + wr + (m << 4) + (lh << 2) + j;
                float v = acc[m][n][j] + bb;
                const int base = lane & ~3;
                float gi = __shfl(v, base, 64);
                float gf = __shfl(v, base | 1, 64);
                float gg = __shfl(v, base | 2, 64);
                float go = __shfl(v, base | 3, 64);
                if ((lane & 3) == 0) {
                    float si = 1.f / (1.f + expf(-gi));
                    float sf = 1.f / (1.f + expf(-gf));
                    float so = 1.f / (1.f + expf(-go));
                    size_t idx = ((size_t)r << 9) + u;
                    float cv = sf * cstate[idx] + si * tanhf(gg);
                    cstate[idx] = cv;
                    h_out[idx] = so * tanhf(cv);
                }
            }
        }
    }
}

// softmax over 49 per n from 8-way partials, then v_emb[n,h] = sum_k att[k]*img[n,k,h]
__global__ __launch_bounds__(256)
void attn_vemb_kernel(const float* __restrict__ partial, const float* __restrict__ img,
                      float* __restrict__ v_emb)
{
    __shared__ float satt[49];
    const int n = blockIdx.x;
    const int tid = threadIdx.x;
    if (tid < 64) {
        float v = -1e30f;
        if (tid < 49) {
            const float* pp = partial + ((size_t)n * 49 + tid) * 8;
            v = ((pp[0] + pp[1]) + (pp[2] + pp[3])) + ((pp[4] + pp[5]) + (pp[6] + pp[7]));
        }
        float m = v;
#pragma unroll
        for (int off = 32; off; off >>= 1) m = fmaxf(m, __shfl_xor(m, off, 64));
        float e = (tid < 49) ? expf(v - m) : 0.f;
        float s = e;
#pragma unroll
        for (int off = 32; off; off >>= 1) s += __shfl_xor(s, off, 64);
        if (tid < 49) satt[tid] = e / s;
    }
    __syncthreads();
    const float2* ip = (const float2*)(img + (size_t)n * 49 * 512);
    float2 s2 = make_float2(0.f, 0.f);
    for (int k = 0; k < 49; ++k) {
        float2 v = ip[k * 256 + tid];
        float a = satt[k];
        s2.x = fmaf(a, v.x, s2.x);
        s2.y = fmaf(a, v.y, s2.y);
    }
    ((float2*)(v_emb + (size_t)n * 512))[tid] = s2;
}

__global__ __launch_bounds__(256)
void g0build_kernel(const float* __restrict__ P, const float* __restrict__ Q,
                    const float* __restrict__ b0, float* __restrict__ g0)
{
    int id = blockIdx.x * 256 + threadIdx.x;   // < 9216*512
    int cc = id & 511;
    int r = id >> 9;
    int j = r % 6;
    int t = r / 6;
    int i = t % 6;
    int b = t / 6;
    float v = P[((size_t)(b * 6 + j) << 9) + cc] + Q[((size_t)(b * 6 + i) << 9) + cc] + b0[cc];
    g0[id] = fmaxf(v, 0.f);
}

__global__ __launch_bounds__(256)
void gsum_kernel(const float* __restrict__ g, float* __restrict__ out)
{
    int id = blockIdx.x * 256 + threadIdx.x;   // < 256*512
    int b = id >> 9, hh = id & 511;
    const float* p = g + (size_t)b * 36 * 512 + hh;
    float s = 0.f;
#pragma unroll
    for (int i = 0; i < 36; ++i) s += p[i * 512];
    out[id] = s;
}

__global__ __launch_bounds__(256)
void l2norm_kernel(const float* __restrict__ in, float* __restrict__ out)
{
    int b = blockIdx.x;
    int tid = threadIdx.x;
    float v0 = in[(size_t)b * 512 + tid];
    float v1 = in[(size_t)b * 512 + 256 + tid];
    float s = v0 * v0 + v1 * v1;
#pragma unroll
    for (int off = 32; off; off >>= 1) s += __shfl_down(s, off, 64);
    __shared__ float ps[4];
    if ((tid & 63) == 0) ps[tid >> 6] = s;
    __syncthreads();
    float tot = ps[0] + ps[1] + ps[2] + ps[3];
    float inv = 1.f / sqrtf(tot);
    out[(size_t)b * 512 + tid] = v0 * inv;
    out[(size_t)b * 512 + 256 + tid] = v1 * inv;
}

extern "C" void kernel_launch(void* const* d_in, const int* in_sizes, int n_in,
                              void* d_out, int out_size, void* d_ws, size_t ws_size,
                              hipStream_t stream)
{
    (void)in_sizes; (void)n_in; (void)out_size; (void)ws_size;
    const float* img    = (const float*)d_in[0];
    const int*   toks   = (const int*)d_in[1];
    const float* qword  = (const float*)d_in[2];
    const float* Wih_f  = (const float*)d_in[3];
    const float* Whh_f  = (const float*)d_in[4];
    const float* bih_f  = (const float*)d_in[5];
    const float* bhh_f  = (const float*)d_in[6];
    const float* Wih_b  = (const float*)d_in[7];
    const float* Whh_b  = (const float*)d_in[8];
    const float* bih_b  = (const float*)d_in[9];
    const float* bhh_b  = (const float*)d_in[10];
    const float* proj_W = (const float*)d_in[11];
    const float* proj_b = (const float*)d_in[12];
    const float* vatt_vW = (const float*)d_in[13];
    const float* vatt_vb = (const float*)d_in[14];
    const float* vatt_qW = (const float*)d_in[15];
    const float* vatt_qb = (const float*)d_in[16];
    const float* vatt_oW = (const float*)d_in[17];
    const float* qnet_W = (const float*)d_in[19];
    const float* qnet_b = (const float*)d_in[20];
    const float* vnet_W = (const float*)d_in[21];
    const float* vnet_b = (const float*)d_in[22];
    const float* cls_W1 = (const float*)d_in[23];
    const float* cls_b1 = (const float*)d_in[24];
    const float* cls_W2 = (const float*)d_in[25];
    const float* cls_b2 = (const float*)d_in[26];
    const float* g0_W   = (const float*)d_in[27];
    const float* g0_b   = (const float*)d_in[28];
    const float* g1_W   = (const float*)d_in[29];
    const float* g1_b   = (const float*)d_in[30];
    const float* g2_W   = (const float*)d_in[31];
    const float* g2_b   = (const float*)d_in[32];
    const float* g3_W   = (const float*)d_in[33];
    const float* g3_b   = (const float*)d_in[34];
    const float* f0_W   = (const float*)d_in[35];
    const float* f0_b   = (const float*)d_in[36];
    const float* f1_W   = (const float*)d_in[37];
    const float* f1_b   = (const float*)d_in[38];

    float* out_logits = (float*)d_out;                  // [1536,2001]
    float* out_rec    = (float*)d_out + 1536 * 2001;    // [256,512]

    const size_t FB = 786432;  // 1536*512
    float* zone = (float*)d_ws;
    // post-LSTM buffers
    float* gA    = zone;                        // 4718592
    float* gB    = zone + 4718592;              // 4718592
    float* hid1  = zone + 9437184;              // 1572864
    float* Pb    = zone + 11010048;             // 786432
    float* Qb    = zone + 11796480;             // 786432
    float* gsumb = zone + 12582912;             // 131072
    float* f0o   = zone + 12713984;             // 131072
    float* rectb = zone + 12845056;             // 131072
    float* p = zone + 12976128;
    auto alloc = [&](size_t nf) { float* q = p; p += nf; return q; };
    float* hP0   = alloc(FB);       // final h_f
    float* hP2   = alloc(FB);       // final h_b
    float* joint = alloc(FB);
    float* partial = alloc(602112); // 75264*8
    short* WbfF  = (short*)alloc(851968);   // [2048][832] bf16 = 1,703,936 shorts
    short* WbfB  = (short*)alloc(851968);
    float* biasF = alloc(2048);
    float* biasB = alloc(2048);
    // LSTM-phase aliases inside gA (gA only used post-LSTM)
    float* hP1 = gA;
    float* hP3 = gA + FB;
    float* cF  = gA + 2 * FB;
    float* cB  = gA + 3 * FB;
    // post-LSTM aliases (dead-before-host-write verified)
    float* q_emb  = Pb;          // dead after qnet (before P-GEMM)
    float* swq    = hid1;        // dead after attn logits (before cls1)
    float* q_repr = gA;          // dead after vnet (before g0build)
    float* v_emb  = gA + FB;     // dead after vnet

    auto gemm = [&](const float* A1, const int* idx1, int idxs, int lda1, int k1,
                    const float* W1, int ldw1,
                    const float* A2, int lda2, int k2, const float* W2, int ldw2,
                    const float* b1, const float* b2, const float* mv, const float* mulp,
                    float* Cp, int ldc, int M, int N, int relu) {
        dim3 g((N + BT - 1) / BT, (M + BT - 1) / BT);
        hipLaunchKernelGGL(mfma_gemm_kernel, g, dim3(256), 0, stream,
                           A1, idx1, idxs, lda1, k1, W1, ldw1, A2, lda2, k2, W2, ldw2,
                           b1, b2, mv, mulp, Cp, ldc, M, N, relu, 0);
    };

    const int NR = 1536;
    // ---- weight reorders ----
    hipLaunchKernelGGL(lstm_reorder_kernel, dim3(4096), dim3(256), 0, stream,
                       Wih_f, Whh_f, bih_f, bhh_f, WbfF, biasF);
    hipLaunchKernelGGL(lstm_reorder_kernel, dim3(4096), dim3(256), 0, stream,
                       Wih_b, Whh_b, bih_b, bhh_b, WbfB, biasB);
    // ---- bidirectional LSTM: 10 fused steps (F and B in one launch via z) ----
    hipMemsetAsync(hP0, 0, FB * sizeof(float), stream);
    hipMemsetAsync(hP2, 0, FB * sizeof(float), stream);
    hipMemsetAsync(cF, 0, FB * sizeof(float), stream);
    hipMemsetAsync(cB, 0, FB * sizeof(float), stream);
    {
        float *fi = hP0, *fo = hP1, *bi = hP2, *bo = hP3;
        for (int t = 0; t < 10; ++t) {
            hipLaunchKernelGGL(lstm_step2_kernel, dim3(32, 24, 2), dim3(256), 0, stream,
                               fi, bi, WbfF, WbfB, biasF, biasB, qword, toks, t, 9 - t,
                               fo, bo, cF, cB);
            float* tmp = fi; fi = fo; fo = tmp;
            tmp = bi; bi = bo; bo = tmp;
        }
    }   // 10 swaps (even): final h_f in hP0, h_b in hP2

    // q_emb = [h_f|h_b] @ proj_W^T + proj_b
    gemm(hP0, nullptr, 0, 512, 512, proj_W, 1024,
         hP2, 512, 512, proj_W + 512, 1024,
         proj_b, nullptr, nullptr, nullptr, q_emb, 512, NR, 512, 0);
    // swq = relu(q_emb @ qW^T + qb) * oW   (fused)
    gemm(q_emb, nullptr, 0, 512, 512, vatt_qW, 512, nullptr, 0, 0, nullptr, 0,
         vatt_qb, nullptr, vatt_oW, nullptr, swq, 512, NR, 512, 1);
    // attention logits: XCD-swizzled 1D grid (mode 1) -> 8-way partials
    hipLaunchKernelGGL(mfma_gemm_kernel, dim3(9408), dim3(256), 0, stream,
                       img, (const int*)nullptr, 0, 512, 512, vatt_vW, 512,
                       (const float*)nullptr, 0, 0, (const float*)nullptr, 0,
                       vatt_vb, (const float*)nullptr, (const float*)nullptr, swq,
                       partial, 512, 75264, 512, 0, 1);
    hipLaunchKernelGGL(attn_vemb_kernel, dim3(1536), dim3(256), 0, stream,
                       partial, img, v_emb);
    // joint = relu(q_emb@qnet^T+b) * relu(v_emb@vnet^T+b)
    gemm(q_emb, nullptr, 0, 512, 512, qnet_W, 512, nullptr, 0, 0, nullptr, 0,
         qnet_b, nullptr, nullptr, nullptr, q_repr, 512, NR, 512, 1);
    gemm(v_emb, nullptr, 0, 512, 512, vnet_W, 512, nullptr, 0, 0, nullptr, 0,
         vnet_b, nullptr, nullptr, q_repr, joint, 512, NR, 512, 1);
    // classifier
    gemm(joint, nullptr, 0, 512, 512, cls_W1, 512, nullptr, 0, 0, nullptr, 0,
         cls_b1, nullptr, nullptr, nullptr, hid1, 1024, NR, 1024, 1);
    gemm(hid1, nullptr, 0, 1024, 1024, cls_W2, 1024, nullptr, 0, 0, nullptr, 0,
         cls_b2, nullptr, nullptr, nullptr, out_logits, 2001, NR, 2001, 0);
    // relation network: g0 factored via P (g0_W[:, :512]) and Q (g0_W[:, 512:])
    gemm(joint, nullptr, 0, 512, 512, g0_W, 1024, nullptr, 0, 0, nullptr, 0,
         nullptr, nullptr, nullptr, nullptr, Pb, 512, NR, 512, 0);
    gemm(joint, nullptr, 0, 512, 512, g0_W + 512, 1024, nullptr, 0, 0, nullptr, 0,
         nullptr, nullptr, nullptr, nullptr, Qb, 512, NR, 512, 0);
    hipLaunchKernelGGL(g0build_kernel, dim3(18432), dim3(256), 0, stream, Pb, Qb, g0_b, gA);
    gemm(gA, nullptr, 0, 512, 512, g1_W, 512, nullptr, 0, 0, nullptr, 0,
         g1_b, nullptr, nullptr, nullptr, gB, 512, 9216, 512, 1);
    gemm(gB, nullptr, 0, 512, 512, g2_W, 512, nullptr, 0, 0, nullptr, 0,
         g2_b, nullptr, nullptr, nullptr, gA, 512, 9216, 512, 1);
    gemm(gA, nullptr, 0, 512, 512, g3_W, 512, nullptr, 0, 0, nullptr, 0,
         g3_b, nullptr, nullptr, nullptr, gB, 512, 9216, 512, 1);
    hipLaunchKernelGGL(gsum_kernel, dim3(512), dim3(256), 0, stream, gB, gsumb);
    gemm(gsumb, nullptr, 0, 512, 512, f0_W, 512, nullptr, 0, 0, nullptr, 0,
         f0_b, nullptr, nullptr, nullptr, f0o, 512, 256, 512, 1);
    gemm(f0o, nullptr, 0, 512, 512, f1_W, 512, nullptr, 0, 0, nullptr, 0,
         f1_b, nullptr, nullptr, nullptr, rectb, 512, 256, 512, 0);
    hipLaunchKernelGGL(l2norm_kernel, dim3(256), dim3(256), 0, stream, rectb, out_rec);
}